// Round 3
// baseline (232.619 us; speedup 1.0000x reference)
//
#include <hip/hip_runtime.h>

typedef unsigned short u16;
typedef unsigned int   u32;
typedef __attribute__((ext_vector_type(8))) short bf16x8;
typedef __attribute__((ext_vector_type(4))) float f32x4;

#define MFMA16(a,b,c) __builtin_amdgcn_mfma_f32_16x16x32_bf16((a),(b),(c),0,0,0)
#define GLD16(gp, lp) __builtin_amdgcn_global_load_lds((const __attribute__((address_space(1))) u32*)(gp), (__attribute__((address_space(3))) u32*)(lp), 16, 0, 0)

#define B_   2
#define NG_  8
#define LS_  512
#define E_   1024
#define NH_  16
#define HD_  64
#define NTOK 8192   // B_*NG_*LS_

__device__ __forceinline__ u16 f2bu(float f){
  u32 u = __builtin_bit_cast(u32, f);
  u32 r = u + 0x7FFFu + ((u >> 16) & 1u);   // RN-even
  return (u16)(r >> 16);
}
__device__ __forceinline__ float b2f(u16 h){
  u32 u = ((u32)h) << 16;
  return __builtin_bit_cast(float, u);
}

// ---------------- fp32 -> bf16 convert (x) ----------------
__global__ __launch_bounds__(256) void k_conv_x(const float* __restrict__ x, u16* __restrict__ xb){
  int i = blockIdx.x * 256 + threadIdx.x;
  float4 v = ((const float4*)x)[i];
  ((ushort4*)xb)[i] = make_ushort4(f2bu(v.x), f2bu(v.y), f2bu(v.z), f2bu(v.w));
}

// ---------------- weight transpose fp32[K][N] -> bf16[N][K] ----------------
__global__ __launch_bounds__(256) void k_transpose(const float* __restrict__ W, u16* __restrict__ WT,
                                                   int Kd, int Nd){
  __shared__ float tile[32][33];
  int tx = threadIdx.x & 31, ty = threadIdx.x >> 5;
  int c0 = blockIdx.x * 32, r0 = blockIdx.y * 32;
  #pragma unroll
  for (int i = 0; i < 4; i++)
    tile[ty + i*8][tx] = W[(size_t)(r0 + ty + i*8) * Nd + c0 + tx];
  __syncthreads();
  #pragma unroll
  for (int i = 0; i < 4; i++)
    WT[(size_t)(c0 + ty + i*8) * Kd + r0 + tx] = f2bu(tile[tx][ty + i*8]);
}

// ---------------- RoPE cos/sin table [LS][HD] ----------------
__global__ __launch_bounds__(256) void k_rope_table(float* __restrict__ ct, float* __restrict__ st){
  int i = blockIdx.x * 256 + threadIdx.x;   // 32768
  int s = i >> 6, d = i & 63, j = d & 31;
  float freq = powf(10000.f, -(4.f * (float)j + 1.f) / 64.f);
  float th = (float)s * freq;
  ct[i] = cosf(th);
  st[i] = sinf(th);
}

// ---------------- m97-style bf16 GEMM: C[M,N] = A[M,K] * Bt[N,K]^T ----------------
template <typename OutT>
__global__ __launch_bounds__(256) void k_gemm_bt(const u16* __restrict__ A, const u16* __restrict__ Bt,
                                                 OutT* __restrict__ C, int M, int N, int K){
  int nbn = N >> 7;
  // bijective XCD swizzle (launcher guarantees gridDim.x % 8 == 0)
  int cpx = gridDim.x >> 3;
  int bid = (blockIdx.x & 7) * cpx + (blockIdx.x >> 3);
  int tm = bid / nbn, tn = bid % nbn;
  int tid = threadIdx.x;
  int w = tid >> 6, l = tid & 63;
  int lr = l & 15, lg = l >> 4;
  int wm = (w >> 1) * 64, wn = (w & 1) * 64;

  __shared__ u16 As[128 * 32];   // linear (global_load_lds requires it)
  __shared__ u16 Bs[128 * 32];

  const u16* Ab = A  + (size_t)(tm * 128) * K;
  const u16* Bb = Bt + (size_t)(tn * 128) * K;

  f32x4 acc[4][4] = {};

  for (int k0 = 0; k0 < K; k0 += 32){
    __syncthreads();
    #pragma unroll
    for (int p = 0; p < 2; p++){
      int c = p * 256 + tid;
      int r = c >> 2, cc = (c & 3) * 8;
      GLD16(Ab + (size_t)r * K + k0 + cc, &As[c * 8]);
      GLD16(Bb + (size_t)r * K + k0 + cc, &Bs[c * 8]);
    }
    __syncthreads();

    bf16x8 a[4], b[4];
    #pragma unroll
    for (int i = 0; i < 4; i++) a[i] = *(const bf16x8*)&As[(wm + i*16 + lr) * 32 + lg * 8];
    #pragma unroll
    for (int j = 0; j < 4; j++) b[j] = *(const bf16x8*)&Bs[(wn + j*16 + lr) * 32 + lg * 8];
    #pragma unroll
    for (int i = 0; i < 4; i++)
      #pragma unroll
      for (int j = 0; j < 4; j++)
        acc[i][j] = MFMA16(a[i], b[j], acc[i][j]);
  }

  #pragma unroll
  for (int i = 0; i < 4; i++)
    #pragma unroll
    for (int j = 0; j < 4; j++)
      #pragma unroll
      for (int r = 0; r < 4; r++){
        int row = tm * 128 + wm + i * 16 + lg * 4 + r;
        int col = tn * 128 + wn + j * 16 + lr;
        float v = acc[i][j][r];
        if constexpr (sizeof(OutT) == 2) C[(size_t)row * N + col] = f2bu(v);
        else                             C[(size_t)row * N + col] = v;
      }
}

// ---------------- RMSNorm + ln_w + RoPE + head split (q scaled by 1/8) ----------------
__global__ __launch_bounds__(256) void k_norm_rope(const u16* __restrict__ qkv, const float* __restrict__ lnw,
                                                   const float* __restrict__ ct, const float* __restrict__ st,
                                                   u16* __restrict__ qh, u16* __restrict__ kh, u16* __restrict__ vh){
  int tok = blockIdx.x;
  int t = threadIdx.x;
  int s = tok & (LS_ - 1);
  int bg = tok >> 9;
  const u16* row = qkv + (size_t)tok * 3072;
  int e0 = t * 4;

  ushort4 q4 = *(const ushort4*)&row[e0];
  ushort4 k4 = *(const ushort4*)&row[1024 + e0];
  ushort4 v4 = *(const ushort4*)&row[2048 + e0];
  float qf[4] = {b2f(q4.x), b2f(q4.y), b2f(q4.z), b2f(q4.w)};
  float kf[4] = {b2f(k4.x), b2f(k4.y), b2f(k4.z), b2f(k4.w)};

  float qss = 0.f, kss = 0.f;
  #pragma unroll
  for (int j = 0; j < 4; j++){ qss += qf[j]*qf[j]; kss += kf[j]*kf[j]; }
  #pragma unroll
  for (int o = 32; o; o >>= 1){ qss += __shfl_down(qss, o); kss += __shfl_down(kss, o); }
  __shared__ float redq[4], redk[4];
  if ((t & 63) == 0){ redq[t >> 6] = qss; redk[t >> 6] = kss; }
  __syncthreads();
  float qsum = redq[0] + redq[1] + redq[2] + redq[3];
  float ksum = redk[0] + redk[1] + redk[2] + redk[3];
  float qr = rsqrtf(qsum * (1.f / 1024.f) + 1e-6f);
  float kr = rsqrtf(ksum * (1.f / 1024.f) + 1e-6f);

  float qn[4], kn[4];
  #pragma unroll
  for (int j = 0; j < 4; j++){
    float wv = lnw[e0 + j];
    qn[j] = qf[j] * qr * wv;
    kn[j] = kf[j] * kr * wv;
  }
  int d0 = e0 & 63, h = e0 >> 6;
  const float* cr = ct + s * 64 + d0;
  const float* sr = st + s * 64 + d0;
  float qo[4], ko[4];
  #pragma unroll
  for (int p = 0; p < 4; p += 2){
    float c0 = cr[p], s0 = sr[p], c1 = cr[p+1], s1 = sr[p+1];
    qo[p]   = qn[p]   * c0 - qn[p+1] * s0;
    qo[p+1] = qn[p+1] * c1 + qn[p]   * s1;
    ko[p]   = kn[p]   * c0 - kn[p+1] * s0;
    ko[p+1] = kn[p+1] * c1 + kn[p]   * s1;
  }
  size_t oidx = (((size_t)bg * NH_ + h) * LS_ + s) * HD_ + d0;
  *(ushort4*)&qh[oidx] = make_ushort4(f2bu(qo[0]*0.125f), f2bu(qo[1]*0.125f), f2bu(qo[2]*0.125f), f2bu(qo[3]*0.125f));
  *(ushort4*)&kh[oidx] = make_ushort4(f2bu(ko[0]), f2bu(ko[1]), f2bu(ko[2]), f2bu(ko[3]));
  *(ushort4*)&vh[oidx] = v4;
}

// ---------------- V transpose: vh [head][s][d] -> vt [head][d][s] ----------------
__global__ __launch_bounds__(256) void k_vt(const u16* __restrict__ vh, u16* __restrict__ vt){
  int head = blockIdx.x >> 3, sb = blockIdx.x & 7;
  int s0 = sb * 64;
  __shared__ u16 t[64 * 72];
  const u16* src = vh + (size_t)head * LS_ * HD_ + (size_t)s0 * HD_;
  u16* dst = vt + (size_t)head * HD_ * LS_;
  #pragma unroll
  for (int p = 0; p < 2; p++){
    int idx = p * 256 + threadIdx.x;
    int r = idx >> 3, c8 = (idx & 7) * 8;
    *(bf16x8*)&t[r * 72 + c8] = *(const bf16x8*)&src[r * HD_ + c8];
  }
  __syncthreads();
  #pragma unroll
  for (int p = 0; p < 2; p++){
    int idx = p * 256 + threadIdx.x;
    int d = idx >> 3, s8 = (idx & 7) * 8;
    u16 tmp[8];
    #pragma unroll
    for (int j = 0; j < 8; j++) tmp[j] = t[(s8 + j) * 72 + d];
    *(bf16x8*)&dst[(size_t)d * LS_ + s0 + s8] = *(bf16x8*)tmp;
  }
}

// ---------------- causal flash attention: independent waves, no barriers ----------------
__global__ __launch_bounds__(256) void k_attn(const u16* __restrict__ qh, const u16* __restrict__ kh,
                                              const u16* __restrict__ vt, u16* __restrict__ ytok){
  int bid = blockIdx.x;
  int head = bid >> 2, qb = 3 - (bid & 3);    // heavy q-blocks dispatched first
  int tid = threadIdx.x;
  int w = tid >> 6, l = tid & 63;
  int lr = l & 15, lg = l >> 4;
  const u16* Qp = qh + (size_t)head * LS_ * HD_;
  const u16* Kp = kh + (size_t)head * LS_ * HD_;
  const u16* Vp = vt + (size_t)head * HD_ * LS_;   // [d][s]
  int bg = head >> 4, h = head & 15;
  u16* Yb = ytok + (size_t)bg * LS_ * E_ + h * HD_;

  int q0 = qb * 128 + w * 32;   // wave owns 32 q rows, fully independent
  bf16x8 aq[2][2];
  #pragma unroll
  for (int mi = 0; mi < 2; mi++)
    #pragma unroll
    for (int kk = 0; kk < 2; kk++)
      aq[mi][kk] = *(const bf16x8*)&Qp[(q0 + mi*16 + lr) * 64 + kk * 32 + lg * 8];

  __shared__ u16 Pl[4][32 * 72];       // per-wave P relayout buffer (in-wave ordering only)

  f32x4 o[2][4] = {};
  float mrun[2][4], lrun[2][4];
  #pragma unroll
  for (int mi = 0; mi < 2; mi++)
    #pragma unroll
    for (int r = 0; r < 4; r++){ mrun[mi][r] = -1e30f; lrun[mi][r] = 0.f; }

  int ntw = (q0 >> 6) + 1;     // exact tile count this wave needs
  for (int tkv = 0; tkv < ntw; tkv++){
    int kv0 = tkv * 64;
    // S = Q K^T, K fragments straight from global (L1/L2-resident)
    f32x4 sa[2][4] = {};
    __builtin_amdgcn_s_setprio(1);
    #pragma unroll
    for (int nk = 0; nk < 4; nk++){
      bf16x8 b0 = *(const bf16x8*)&Kp[(kv0 + nk*16 + lr) * 64 + lg * 8];
      bf16x8 b1 = *(const bf16x8*)&Kp[(kv0 + nk*16 + lr) * 64 + 32 + lg * 8];
      #pragma unroll
      for (int mi = 0; mi < 2; mi++){
        sa[mi][nk] = MFMA16(aq[mi][0], b0, sa[mi][nk]);
        sa[mi][nk] = MFMA16(aq[mi][1], b1, sa[mi][nk]);
      }
    }
    __builtin_amdgcn_s_setprio(0);
    // causal mask (diagonal tiles only)
    if (kv0 + 63 > q0){
      #pragma unroll
      for (int mi = 0; mi < 2; mi++)
        #pragma unroll
        for (int nk = 0; nk < 4; nk++)
          #pragma unroll
          for (int r = 0; r < 4; r++){
            int qg = q0 + mi*16 + lg*4 + r;
            int kg = kv0 + nk*16 + lr;
            if (kg > qg) sa[mi][nk][r] = -1e30f;
          }
    }
    // online softmax
    #pragma unroll
    for (int mi = 0; mi < 2; mi++){
      #pragma unroll
      for (int r = 0; r < 4; r++){
        float v = fmaxf(fmaxf(sa[mi][0][r], sa[mi][1][r]), fmaxf(sa[mi][2][r], sa[mi][3][r]));
        #pragma unroll
        for (int xm = 1; xm < 16; xm <<= 1) v = fmaxf(v, __shfl_xor(v, xm));
        float mnew = fmaxf(mrun[mi][r], v);
        float alpha = __expf(mrun[mi][r] - mnew);
        mrun[mi][r] = mnew;
        float psum = 0.f;
        #pragma unroll
        for (int nk = 0; nk < 4; nk++){
          float pv = __expf(sa[mi][nk][r] - mnew);
          sa[mi][nk][r] = pv;
          psum += pv;
        }
        #pragma unroll
        for (int xm = 1; xm < 16; xm <<= 1) psum += __shfl_xor(psum, xm);
        lrun[mi][r] = lrun[mi][r] * alpha + psum;
        #pragma unroll
        for (int nd = 0; nd < 4; nd++) o[mi][nd][r] *= alpha;
      }
      // P (C-layout) -> per-wave LDS for A-layout reads
      #pragma unroll
      for (int nk = 0; nk < 4; nk++)
        #pragma unroll
        for (int r = 0; r < 4; r++)
          Pl[w][(mi*16 + lg*4 + r) * 72 + nk*16 + lr] = f2bu(sa[mi][nk][r]);
    }
    // O += P @ V, V^T fragments straight from global
    __builtin_amdgcn_s_setprio(1);
    #pragma unroll
    for (int kk = 0; kk < 2; kk++){
      bf16x8 ap[2];
      #pragma unroll
      for (int mi = 0; mi < 2; mi++)
        ap[mi] = *(const bf16x8*)&Pl[w][(mi*16 + lr) * 72 + kk * 32 + lg * 8];
      #pragma unroll
      for (int nd = 0; nd < 4; nd++){
        bf16x8 bv = *(const bf16x8*)&Vp[(nd*16 + lr) * 512 + kv0 + kk * 32 + lg * 8];
        #pragma unroll
        for (int mi = 0; mi < 2; mi++)
          o[mi][nd] = MFMA16(ap[mi], bv, o[mi][nd]);
      }
    }
    __builtin_amdgcn_s_setprio(0);
  }
  // finalize: divide by l, store to token layout
  #pragma unroll
  for (int mi = 0; mi < 2; mi++){
    float inv[4];
    #pragma unroll
    for (int r = 0; r < 4; r++) inv[r] = 1.f / lrun[mi][r];
    #pragma unroll
    for (int nd = 0; nd < 4; nd++)
      #pragma unroll
      for (int r = 0; r < 4; r++){
        int qg = q0 + mi*16 + lg*4 + r;
        Yb[(size_t)qg * E_ + nd*16 + lr] = f2bu(o[mi][nd][r] * inv[r]);
      }
  }
}

extern "C" void kernel_launch(void* const* d_in, const int* in_sizes, int n_in,
                              void* d_out, int out_size, void* d_ws, size_t ws_size,
                              hipStream_t stream){
  const float* x     = (const float*)d_in[0];
  const float* Wqkv  = (const float*)d_in[1];
  const float* lnw   = (const float*)d_in[2];
  const float* Wproj = (const float*)d_in[3];
  float* out = (float*)d_out;   // reference output dtype is float32

  u16* p = (u16*)d_ws;
  u16* xb     = p; p += (size_t)NTOK * E_;        // reused as ytok after GEMM1
  u16* wqkvT  = p; p += (size_t)3 * E_ * E_;
  u16* wprojT = p; p += (size_t)E_ * E_;
  u16* qkv    = p; p += (size_t)NTOK * 3 * E_;    // dead after norm_rope -> reused for vT
  u16* qhp    = p; p += (size_t)NTOK * E_;
  u16* khp    = p; p += (size_t)NTOK * E_;
  u16* vhp    = p; p += (size_t)NTOK * E_;
  float* ct = (float*)p;
  float* st = ct + LS_ * HD_;
  u16* vtp = qkv;   // [head][d][s], aliases dead qkv buffer

  k_conv_x<<<8192, 256, 0, stream>>>(x, xb);
  k_transpose<<<dim3(96, 32), 256, 0, stream>>>(Wqkv, wqkvT, 1024, 3072);
  k_transpose<<<dim3(32, 32), 256, 0, stream>>>(Wproj, wprojT, 1024, 1024);
  k_rope_table<<<128, 256, 0, stream>>>(ct, st);
  k_gemm_bt<u16><<<64 * 24, 256, 0, stream>>>(xb, wqkvT, qkv, NTOK, 3 * E_, E_);
  k_norm_rope<<<NTOK, 256, 0, stream>>>(qkv, lnw, ct, st, qhp, khp, vhp);
  k_vt<<<2048, 256, 0, stream>>>(vhp, vtp);
  k_attn<<<1024, 256, 0, stream>>>(qhp, khp, vtp, xb);           // xb now = y_tok
  k_gemm_bt<float><<<64 * 8, 256, 0, stream>>>(xb, wprojT, out, NTOK, E_, E_);
}

// Round 4
// 224.024 us; speedup vs baseline: 1.0384x; 1.0384x over previous
//
#include <hip/hip_runtime.h>

typedef unsigned short u16;
typedef unsigned int   u32;
typedef __attribute__((ext_vector_type(8))) short bf16x8;
typedef __attribute__((ext_vector_type(4))) float f32x4;

#define MFMA16(a,b,c) __builtin_amdgcn_mfma_f32_16x16x32_bf16((a),(b),(c),0,0,0)
#define GLD16(gp, lp) __builtin_amdgcn_global_load_lds((const __attribute__((address_space(1))) u32*)(gp), (__attribute__((address_space(3))) u32*)(lp), 16, 0, 0)

#define B_   2
#define NG_  8
#define LS_  512
#define E_   1024
#define NH_  16
#define HD_  64
#define NTOK 8192   // B_*NG_*LS_

__device__ __forceinline__ u16 f2bu(float f){
  u32 u = __builtin_bit_cast(u32, f);
  u32 r = u + 0x7FFFu + ((u >> 16) & 1u);   // RN-even
  return (u16)(r >> 16);
}
__device__ __forceinline__ float b2f(u16 h){
  u32 u = ((u32)h) << 16;
  return __builtin_bit_cast(float, u);
}

// ---------------- fp32 -> bf16 convert (x) ----------------
__global__ __launch_bounds__(256) void k_conv_x(const float* __restrict__ x, u16* __restrict__ xb){
  int i = blockIdx.x * 256 + threadIdx.x;
  float4 v = ((const float4*)x)[i];
  ((ushort4*)xb)[i] = make_ushort4(f2bu(v.x), f2bu(v.y), f2bu(v.z), f2bu(v.w));
}

// ---------------- weight transpose fp32[K][N] -> bf16[N][K] ----------------
__global__ __launch_bounds__(256) void k_transpose(const float* __restrict__ W, u16* __restrict__ WT,
                                                   int Kd, int Nd){
  __shared__ float tile[32][33];
  int tx = threadIdx.x & 31, ty = threadIdx.x >> 5;
  int c0 = blockIdx.x * 32, r0 = blockIdx.y * 32;
  #pragma unroll
  for (int i = 0; i < 4; i++)
    tile[ty + i*8][tx] = W[(size_t)(r0 + ty + i*8) * Nd + c0 + tx];
  __syncthreads();
  #pragma unroll
  for (int i = 0; i < 4; i++)
    WT[(size_t)(c0 + ty + i*8) * Kd + r0 + tx] = f2bu(tile[tx][ty + i*8]);
}

// ---------------- RoPE cos/sin table [LS][HD] ----------------
__global__ __launch_bounds__(256) void k_rope_table(float* __restrict__ ct, float* __restrict__ st){
  int i = blockIdx.x * 256 + threadIdx.x;   // 32768
  int s = i >> 6, d = i & 63, j = d & 31;
  float freq = powf(10000.f, -(4.f * (float)j + 1.f) / 64.f);
  float th = (float)s * freq;
  ct[i] = cosf(th);
  st[i] = sinf(th);
}

// ---------------- m97-style bf16 GEMM: C[M,N] = A[M,K] * Bt[N,K]^T ----------------
template <typename OutT>
__global__ __launch_bounds__(256) void k_gemm_bt(const u16* __restrict__ A, const u16* __restrict__ Bt,
                                                 OutT* __restrict__ C, int M, int N, int K){
  int nbn = N >> 7;
  int cpx = gridDim.x >> 3;
  int bid = (blockIdx.x & 7) * cpx + (blockIdx.x >> 3);
  int tm = bid / nbn, tn = bid % nbn;
  int tid = threadIdx.x;
  int w = tid >> 6, l = tid & 63;
  int lr = l & 15, lg = l >> 4;
  int wm = (w >> 1) * 64, wn = (w & 1) * 64;

  __shared__ u16 As[128 * 32];   // linear (global_load_lds requires it)
  __shared__ u16 Bs[128 * 32];

  const u16* Ab = A  + (size_t)(tm * 128) * K;
  const u16* Bb = Bt + (size_t)(tn * 128) * K;

  f32x4 acc[4][4] = {};

  for (int k0 = 0; k0 < K; k0 += 32){
    __syncthreads();
    #pragma unroll
    for (int p = 0; p < 2; p++){
      int c = p * 256 + tid;
      int r = c >> 2, cc = (c & 3) * 8;
      GLD16(Ab + (size_t)r * K + k0 + cc, &As[c * 8]);
      GLD16(Bb + (size_t)r * K + k0 + cc, &Bs[c * 8]);
    }
    __syncthreads();

    bf16x8 a[4], b[4];
    #pragma unroll
    for (int i = 0; i < 4; i++) a[i] = *(const bf16x8*)&As[(wm + i*16 + lr) * 32 + lg * 8];
    #pragma unroll
    for (int j = 0; j < 4; j++) b[j] = *(const bf16x8*)&Bs[(wn + j*16 + lr) * 32 + lg * 8];
    #pragma unroll
    for (int i = 0; i < 4; i++)
      #pragma unroll
      for (int j = 0; j < 4; j++)
        acc[i][j] = MFMA16(a[i], b[j], acc[i][j]);
  }

  #pragma unroll
  for (int i = 0; i < 4; i++)
    #pragma unroll
    for (int j = 0; j < 4; j++)
      #pragma unroll
      for (int r = 0; r < 4; r++){
        int row = tm * 128 + wm + i * 16 + lg * 4 + r;
        int col = tn * 128 + wn + j * 16 + lr;
        float v = acc[i][j][r];
        if constexpr (sizeof(OutT) == 2) C[(size_t)row * N + col] = f2bu(v);
        else                             C[(size_t)row * N + col] = v;
      }
}

// ---------------- RMSNorm + ln_w + RoPE + head split (q scaled by 1/8) ----------------
__global__ __launch_bounds__(256) void k_norm_rope(const u16* __restrict__ qkv, const float* __restrict__ lnw,
                                                   const float* __restrict__ ct, const float* __restrict__ st,
                                                   u16* __restrict__ qh, u16* __restrict__ kh, u16* __restrict__ vh){
  int tok = blockIdx.x;
  int t = threadIdx.x;
  int s = tok & (LS_ - 1);
  int bg = tok >> 9;
  const u16* row = qkv + (size_t)tok * 3072;
  int e0 = t * 4;

  ushort4 q4 = *(const ushort4*)&row[e0];
  ushort4 k4 = *(const ushort4*)&row[1024 + e0];
  ushort4 v4 = *(const ushort4*)&row[2048 + e0];
  float qf[4] = {b2f(q4.x), b2f(q4.y), b2f(q4.z), b2f(q4.w)};
  float kf[4] = {b2f(k4.x), b2f(k4.y), b2f(k4.z), b2f(k4.w)};

  float qss = 0.f, kss = 0.f;
  #pragma unroll
  for (int j = 0; j < 4; j++){ qss += qf[j]*qf[j]; kss += kf[j]*kf[j]; }
  #pragma unroll
  for (int o = 32; o; o >>= 1){ qss += __shfl_down(qss, o); kss += __shfl_down(kss, o); }
  __shared__ float redq[4], redk[4];
  if ((t & 63) == 0){ redq[t >> 6] = qss; redk[t >> 6] = kss; }
  __syncthreads();
  float qsum = redq[0] + redq[1] + redq[2] + redq[3];
  float ksum = redk[0] + redk[1] + redk[2] + redk[3];
  float qr = rsqrtf(qsum * (1.f / 1024.f) + 1e-6f);
  float kr = rsqrtf(ksum * (1.f / 1024.f) + 1e-6f);

  float qn[4], kn[4];
  #pragma unroll
  for (int j = 0; j < 4; j++){
    float wv = lnw[e0 + j];
    qn[j] = qf[j] * qr * wv;
    kn[j] = kf[j] * kr * wv;
  }
  int d0 = e0 & 63, h = e0 >> 6;
  const float* cr = ct + s * 64 + d0;
  const float* sr = st + s * 64 + d0;
  float qo[4], ko[4];
  #pragma unroll
  for (int p = 0; p < 4; p += 2){
    float c0 = cr[p], s0 = sr[p], c1 = cr[p+1], s1 = sr[p+1];
    qo[p]   = qn[p]   * c0 - qn[p+1] * s0;
    qo[p+1] = qn[p+1] * c1 + qn[p]   * s1;
    ko[p]   = kn[p]   * c0 - kn[p+1] * s0;
    ko[p+1] = kn[p+1] * c1 + kn[p]   * s1;
  }
  size_t oidx = (((size_t)bg * NH_ + h) * LS_ + s) * HD_ + d0;
  *(ushort4*)&qh[oidx] = make_ushort4(f2bu(qo[0]*0.125f), f2bu(qo[1]*0.125f), f2bu(qo[2]*0.125f), f2bu(qo[3]*0.125f));
  *(ushort4*)&kh[oidx] = make_ushort4(f2bu(ko[0]), f2bu(ko[1]), f2bu(ko[2]), f2bu(ko[3]));
  *(ushort4*)&vh[oidx] = v4;
}

// ---------------- V transpose: vh [head][s][d] -> vt [head][d][s] ----------------
__global__ __launch_bounds__(256) void k_vt(const u16* __restrict__ vh, u16* __restrict__ vt){
  int head = blockIdx.x >> 3, sb = blockIdx.x & 7;
  int s0 = sb * 64;
  __shared__ u16 t[64 * 72];
  const u16* src = vh + (size_t)head * LS_ * HD_ + (size_t)s0 * HD_;
  u16* dst = vt + (size_t)head * HD_ * LS_;
  #pragma unroll
  for (int p = 0; p < 2; p++){
    int idx = p * 256 + threadIdx.x;
    int r = idx >> 3, c8 = (idx & 7) * 8;
    *(bf16x8*)&t[r * 72 + c8] = *(const bf16x8*)&src[r * HD_ + c8];
  }
  __syncthreads();
  #pragma unroll
  for (int p = 0; p < 2; p++){
    int idx = p * 256 + threadIdx.x;
    int d = idx >> 3, s8 = (idx & 7) * 8;
    u16 tmp[8];
    #pragma unroll
    for (int j = 0; j < 8; j++) tmp[j] = t[(s8 + j) * 72 + d];
    *(bf16x8*)&dst[(size_t)d * LS_ + s0 + s8] = *(bf16x8*)tmp;
  }
}

// ---------------- causal flash attention: swapped-QK^T, in-register softmax ----------------
// wave owns 16 q rows; lane holds one q column (q = q0 + (lane&15));
// blocks of 4 waves carry exactly 18 KV-tiles each (perfect balance).
__global__ __launch_bounds__(256) void k_attn(const u16* __restrict__ qh, const u16* __restrict__ kh,
                                              const u16* __restrict__ vt, u16* __restrict__ ytok){
  int bid = blockIdx.x;                 // 2048 blocks
  int head = bid >> 3, pb = bid & 7;
  int tid = threadIdx.x;
  int w = tid >> 6, l = tid & 63;
  int lr = l & 15, lg = l >> 4;
  // wave-job index j in 0..31: {pb, 31-pb, pb+8, 23-pb} -> per-block tiles = 9+9 = 18
  int j = (w & 1) ? (31 - (w >> 1) * 8 - pb) : (pb + (w >> 1) * 8);
  int q0 = j * 16;
  int ntw = (j >> 2) + 1;               // exact KV-tile count for these q rows

  const u16* Qp = qh + (size_t)head * LS_ * HD_;
  const u16* Kp = kh + (size_t)head * LS_ * HD_;
  const u16* Vp = vt + (size_t)head * HD_ * LS_;   // [d][s]
  int bg = head >> 4, h = head & 15;
  u16* Yb = ytok + (size_t)bg * LS_ * E_ + h * HD_;

  // Q fragments (B-operand): B[k=d][col=q], lane holds col=lr, k=lg*8..
  bf16x8 aq[2];
  #pragma unroll
  for (int kk = 0; kk < 2; kk++)
    aq[kk] = *(const bf16x8*)&Qp[(q0 + lr) * 64 + kk * 32 + lg * 8];

  __shared__ u16 Pl[4][16 * 72];        // per-wave P relayout buffer (no barriers)
  u16* Pw = Pl[w];

  f32x4 o[4] = {};                      // O[q=lg*4+r][d=nd*16+lr]
  float mrun = -1e30f, lrun = 0.f;      // per-lane: one q row each

  for (int tkv = 0; tkv < ntw; tkv++){
    int kv0 = tkv * 64;
    // S^T = K Q^T : A=K rows(kv), B=Q cols(q). Lane gets q=lr, kv=kv0+nk*16+lg*4+r.
    f32x4 sa[4] = {};
    __builtin_amdgcn_s_setprio(1);
    #pragma unroll
    for (int nk = 0; nk < 4; nk++){
      bf16x8 k0 = *(const bf16x8*)&Kp[(kv0 + nk*16 + lr) * 64 + lg * 8];
      bf16x8 k1 = *(const bf16x8*)&Kp[(kv0 + nk*16 + lr) * 64 + 32 + lg * 8];
      sa[nk] = MFMA16(k0, aq[0], sa[nk]);
      sa[nk] = MFMA16(k1, aq[1], sa[nk]);
    }
    __builtin_amdgcn_s_setprio(0);
    // causal mask (last tile only)
    if (kv0 + 63 > q0){
      int qg = q0 + lr;
      #pragma unroll
      for (int nk = 0; nk < 4; nk++)
        #pragma unroll
        for (int r = 0; r < 4; r++){
          int kg = kv0 + nk*16 + lg*4 + r;
          if (kg > qg) sa[nk][r] = -1e30f;
        }
    }
    // in-register row max (16 values) + 2-step cross-lg reduce
    float pmax = sa[0][0];
    #pragma unroll
    for (int nk = 0; nk < 4; nk++)
      #pragma unroll
      for (int r = 0; r < 4; r++) pmax = fmaxf(pmax, sa[nk][r]);
    pmax = fmaxf(pmax, __shfl_xor(pmax, 16));
    pmax = fmaxf(pmax, __shfl_xor(pmax, 32));

    float mnew = fmaxf(mrun, pmax);
    float alpha = __expf(mrun - mnew);
    mrun = mnew;

    float psum = 0.f;
    #pragma unroll
    for (int nk = 0; nk < 4; nk++)
      #pragma unroll
      for (int r = 0; r < 4; r++){
        float pv = __expf(sa[nk][r] - mnew);
        sa[nk][r] = pv;
        psum += pv;
      }
    psum += __shfl_xor(psum, 16);
    psum += __shfl_xor(psum, 32);
    lrun = lrun * alpha + psum;

    // rescale O: O's q index is lg*4+r -> fetch alpha from lane (lg*4+r)
    #pragma unroll
    for (int r = 0; r < 4; r++){
      float ar = __shfl(alpha, lg * 4 + r);
      #pragma unroll
      for (int nd = 0; nd < 4; nd++) o[nd][r] *= ar;
    }

    // P (lane-local, kv-strided) -> per-wave LDS [q][kv] for A-fragment reads
    #pragma unroll
    for (int nk = 0; nk < 4; nk++){
      u32 d0 = (u32)f2bu(sa[nk][0]) | ((u32)f2bu(sa[nk][1]) << 16);
      u32 d1 = (u32)f2bu(sa[nk][2]) | ((u32)f2bu(sa[nk][3]) << 16);
      *(u32*)&Pw[lr * 72 + nk * 16 + lg * 4]     = d0;
      *(u32*)&Pw[lr * 72 + nk * 16 + lg * 4 + 2] = d1;
    }
    // O += P @ V : A=P rows(q), B=V^T cols(d)
    bf16x8 pa0 = *(const bf16x8*)&Pw[lr * 72 + lg * 8];
    bf16x8 pa1 = *(const bf16x8*)&Pw[lr * 72 + 32 + lg * 8];
    __builtin_amdgcn_s_setprio(1);
    #pragma unroll
    for (int nd = 0; nd < 4; nd++){
      bf16x8 bv0 = *(const bf16x8*)&Vp[(nd*16 + lr) * 512 + kv0 + lg * 8];
      bf16x8 bv1 = *(const bf16x8*)&Vp[(nd*16 + lr) * 512 + kv0 + 32 + lg * 8];
      o[nd] = MFMA16(pa0, bv0, o[nd]);
      o[nd] = MFMA16(pa1, bv1, o[nd]);
    }
    __builtin_amdgcn_s_setprio(0);
  }

  // finalize: divide by l (redistribute like alpha), store token layout
  float linv = 1.f / lrun;
  #pragma unroll
  for (int r = 0; r < 4; r++){
    float ir = __shfl(linv, lg * 4 + r);
    int qg = q0 + lg * 4 + r;
    #pragma unroll
    for (int nd = 0; nd < 4; nd++)
      Yb[(size_t)qg * E_ + nd * 16 + lr] = f2bu(o[nd][r] * ir);
  }
}

extern "C" void kernel_launch(void* const* d_in, const int* in_sizes, int n_in,
                              void* d_out, int out_size, void* d_ws, size_t ws_size,
                              hipStream_t stream){
  const float* x     = (const float*)d_in[0];
  const float* Wqkv  = (const float*)d_in[1];
  const float* lnw   = (const float*)d_in[2];
  const float* Wproj = (const float*)d_in[3];
  float* out = (float*)d_out;   // reference output dtype is float32

  u16* p = (u16*)d_ws;
  u16* xb     = p; p += (size_t)NTOK * E_;        // reused as ytok after GEMM1
  u16* wqkvT  = p; p += (size_t)3 * E_ * E_;
  u16* wprojT = p; p += (size_t)E_ * E_;
  u16* qkv    = p; p += (size_t)NTOK * 3 * E_;    // dead after norm_rope -> reused for vT
  u16* qhp    = p; p += (size_t)NTOK * E_;
  u16* khp    = p; p += (size_t)NTOK * E_;
  u16* vhp    = p; p += (size_t)NTOK * E_;
  float* ct = (float*)p;
  float* st = ct + LS_ * HD_;
  u16* vtp = qkv;   // [head][d][s], aliases dead qkv buffer

  k_conv_x<<<8192, 256, 0, stream>>>(x, xb);
  k_transpose<<<dim3(96, 32), 256, 0, stream>>>(Wqkv, wqkvT, 1024, 3072);
  k_transpose<<<dim3(32, 32), 256, 0, stream>>>(Wproj, wprojT, 1024, 1024);
  k_rope_table<<<128, 256, 0, stream>>>(ct, st);
  k_gemm_bt<u16><<<64 * 24, 256, 0, stream>>>(xb, wqkvT, qkv, NTOK, 3 * E_, E_);
  k_norm_rope<<<NTOK, 256, 0, stream>>>(qkv, lnw, ct, st, qhp, khp, vhp);
  k_vt<<<2048, 256, 0, stream>>>(vhp, vtp);
  k_attn<<<2048, 256, 0, stream>>>(qhp, khp, vtp, xb);           // xb now = y_tok
  k_gemm_bt<float><<<64 * 8, 256, 0, stream>>>(xb, wprojT, out, NTOK, E_, E_);
}

// Round 5
// 204.303 us; speedup vs baseline: 1.1386x; 1.0965x over previous
//
#include <hip/hip_runtime.h>

typedef unsigned short u16;
typedef unsigned int   u32;
typedef __attribute__((ext_vector_type(8))) short bf16x8;
typedef __attribute__((ext_vector_type(4))) float f32x4;

#define MFMA16(a,b,c) __builtin_amdgcn_mfma_f32_16x16x32_bf16((a),(b),(c),0,0,0)
#define GLD16(gp, lp) __builtin_amdgcn_global_load_lds((const __attribute__((address_space(1))) u32*)(gp), (__attribute__((address_space(3))) u32*)(lp), 16, 0, 0)

#define B_   2
#define NG_  8
#define LS_  512
#define E_   1024
#define NH_  16
#define HD_  64
#define NTOK 8192   // B_*NG_*LS_

__device__ __forceinline__ u16 f2bu(float f){
  u32 u = __builtin_bit_cast(u32, f);
  u32 r = u + 0x7FFFu + ((u >> 16) & 1u);   // RN-even
  return (u16)(r >> 16);
}
__device__ __forceinline__ float b2f(u16 h){
  u32 u = ((u32)h) << 16;
  return __builtin_bit_cast(float, u);
}

// ---------------- fp32 -> bf16 convert (x) ----------------
__global__ __launch_bounds__(256) void k_conv_x(const float* __restrict__ x, u16* __restrict__ xb){
  int i = blockIdx.x * 256 + threadIdx.x;
  float4 v = ((const float4*)x)[i];
  ((ushort4*)xb)[i] = make_ushort4(f2bu(v.x), f2bu(v.y), f2bu(v.z), f2bu(v.w));
}

// ---------------- weight transpose fp32[K][N] -> bf16[N][K] ----------------
__global__ __launch_bounds__(256) void k_transpose(const float* __restrict__ W, u16* __restrict__ WT,
                                                   int Kd, int Nd){
  __shared__ float tile[32][33];
  int tx = threadIdx.x & 31, ty = threadIdx.x >> 5;
  int c0 = blockIdx.x * 32, r0 = blockIdx.y * 32;
  #pragma unroll
  for (int i = 0; i < 4; i++)
    tile[ty + i*8][tx] = W[(size_t)(r0 + ty + i*8) * Nd + c0 + tx];
  __syncthreads();
  #pragma unroll
  for (int i = 0; i < 4; i++)
    WT[(size_t)(c0 + ty + i*8) * Kd + r0 + tx] = f2bu(tile[tx][ty + i*8]);
}

// ---------------- RoPE cos/sin table [LS][HD] ----------------
__global__ __launch_bounds__(256) void k_rope_table(float* __restrict__ ct, float* __restrict__ st){
  int i = blockIdx.x * 256 + threadIdx.x;   // 32768
  int s = i >> 6, d = i & 63, j = d & 31;
  float freq = powf(10000.f, -(4.f * (float)j + 1.f) / 64.f);
  float th = (float)s * freq;
  ct[i] = cosf(th);
  st[i] = sinf(th);
}

// ---------------- m97-style bf16 GEMM: C[M,N] = A[M,K] * Bt[N,K]^T ----------------
template <typename OutT>
__global__ __launch_bounds__(256) void k_gemm_bt(const u16* __restrict__ A, const u16* __restrict__ Bt,
                                                 OutT* __restrict__ C, int M, int N, int K){
  int nbn = N >> 7;
  int cpx = gridDim.x >> 3;
  int bid = (blockIdx.x & 7) * cpx + (blockIdx.x >> 3);
  int tm = bid / nbn, tn = bid % nbn;
  int tid = threadIdx.x;
  int w = tid >> 6, l = tid & 63;
  int lr = l & 15, lg = l >> 4;
  int wm = (w >> 1) * 64, wn = (w & 1) * 64;

  __shared__ u16 As[128 * 32];   // linear (global_load_lds requires it)
  __shared__ u16 Bs[128 * 32];

  const u16* Ab = A  + (size_t)(tm * 128) * K;
  const u16* Bb = Bt + (size_t)(tn * 128) * K;

  f32x4 acc[4][4] = {};

  for (int k0 = 0; k0 < K; k0 += 32){
    __syncthreads();
    #pragma unroll
    for (int p = 0; p < 2; p++){
      int c = p * 256 + tid;
      int r = c >> 2, cc = (c & 3) * 8;
      GLD16(Ab + (size_t)r * K + k0 + cc, &As[c * 8]);
      GLD16(Bb + (size_t)r * K + k0 + cc, &Bs[c * 8]);
    }
    __syncthreads();

    bf16x8 a[4], b[4];
    #pragma unroll
    for (int i = 0; i < 4; i++) a[i] = *(const bf16x8*)&As[(wm + i*16 + lr) * 32 + lg * 8];
    #pragma unroll
    for (int j = 0; j < 4; j++) b[j] = *(const bf16x8*)&Bs[(wn + j*16 + lr) * 32 + lg * 8];
    #pragma unroll
    for (int i = 0; i < 4; i++)
      #pragma unroll
      for (int j = 0; j < 4; j++)
        acc[i][j] = MFMA16(a[i], b[j], acc[i][j]);
  }

  #pragma unroll
  for (int i = 0; i < 4; i++)
    #pragma unroll
    for (int j = 0; j < 4; j++)
      #pragma unroll
      for (int r = 0; r < 4; r++){
        int row = tm * 128 + wm + i * 16 + lg * 4 + r;
        int col = tn * 128 + wn + j * 16 + lr;
        float v = acc[i][j][r];
        if constexpr (sizeof(OutT) == 2) C[(size_t)row * N + col] = f2bu(v);
        else                             C[(size_t)row * N + col] = v;
      }
}

// ---------------- RMSNorm + ln_w + RoPE + head split (q scaled by 1/8) ----------------
__global__ __launch_bounds__(256) void k_norm_rope(const u16* __restrict__ qkv, const float* __restrict__ lnw,
                                                   const float* __restrict__ ct, const float* __restrict__ st,
                                                   u16* __restrict__ qh, u16* __restrict__ kh, u16* __restrict__ vh){
  int tok = blockIdx.x;
  int t = threadIdx.x;
  int s = tok & (LS_ - 1);
  int bg = tok >> 9;
  const u16* row = qkv + (size_t)tok * 3072;
  int e0 = t * 4;

  ushort4 q4 = *(const ushort4*)&row[e0];
  ushort4 k4 = *(const ushort4*)&row[1024 + e0];
  ushort4 v4 = *(const ushort4*)&row[2048 + e0];
  float qf[4] = {b2f(q4.x), b2f(q4.y), b2f(q4.z), b2f(q4.w)};
  float kf[4] = {b2f(k4.x), b2f(k4.y), b2f(k4.z), b2f(k4.w)};

  float qss = 0.f, kss = 0.f;
  #pragma unroll
  for (int j = 0; j < 4; j++){ qss += qf[j]*qf[j]; kss += kf[j]*kf[j]; }
  #pragma unroll
  for (int o = 32; o; o >>= 1){ qss += __shfl_down(qss, o); kss += __shfl_down(kss, o); }
  __shared__ float redq[4], redk[4];
  if ((t & 63) == 0){ redq[t >> 6] = qss; redk[t >> 6] = kss; }
  __syncthreads();
  float qsum = redq[0] + redq[1] + redq[2] + redq[3];
  float ksum = redk[0] + redk[1] + redk[2] + redk[3];
  float qr = rsqrtf(qsum * (1.f / 1024.f) + 1e-6f);
  float kr = rsqrtf(ksum * (1.f / 1024.f) + 1e-6f);

  float qn[4], kn[4];
  #pragma unroll
  for (int j = 0; j < 4; j++){
    float wv = lnw[e0 + j];
    qn[j] = qf[j] * qr * wv;
    kn[j] = kf[j] * kr * wv;
  }
  int d0 = e0 & 63, h = e0 >> 6;
  const float* cr = ct + s * 64 + d0;
  const float* sr = st + s * 64 + d0;
  float qo[4], ko[4];
  #pragma unroll
  for (int p = 0; p < 4; p += 2){
    float c0 = cr[p], s0 = sr[p], c1 = cr[p+1], s1 = sr[p+1];
    qo[p]   = qn[p]   * c0 - qn[p+1] * s0;
    qo[p+1] = qn[p+1] * c1 + qn[p]   * s1;
    ko[p]   = kn[p]   * c0 - kn[p+1] * s0;
    ko[p+1] = kn[p+1] * c1 + kn[p]   * s1;
  }
  size_t oidx = (((size_t)bg * NH_ + h) * LS_ + s) * HD_ + d0;
  *(ushort4*)&qh[oidx] = make_ushort4(f2bu(qo[0]*0.125f), f2bu(qo[1]*0.125f), f2bu(qo[2]*0.125f), f2bu(qo[3]*0.125f));
  *(ushort4*)&kh[oidx] = make_ushort4(f2bu(ko[0]), f2bu(ko[1]), f2bu(ko[2]), f2bu(ko[3]));
  *(ushort4*)&vh[oidx] = v4;
}

// ---------------- V transpose: vh [head][s][d] -> vt [head][d][s] ----------------
__global__ __launch_bounds__(256) void k_vt(const u16* __restrict__ vh, u16* __restrict__ vt){
  int head = blockIdx.x >> 3, sb = blockIdx.x & 7;
  int s0 = sb * 64;
  __shared__ u16 t[64 * 72];
  const u16* src = vh + (size_t)head * LS_ * HD_ + (size_t)s0 * HD_;
  u16* dst = vt + (size_t)head * HD_ * LS_;
  #pragma unroll
  for (int p = 0; p < 2; p++){
    int idx = p * 256 + threadIdx.x;
    int r = idx >> 3, c8 = (idx & 7) * 8;
    *(bf16x8*)&t[r * 72 + c8] = *(const bf16x8*)&src[r * HD_ + c8];
  }
  __syncthreads();
  #pragma unroll
  for (int p = 0; p < 2; p++){
    int idx = p * 256 + threadIdx.x;
    int d = idx >> 3, s8 = (idx & 7) * 8;
    u16 tmp[8];
    #pragma unroll
    for (int j = 0; j < 8; j++) tmp[j] = t[(s8 + j) * 72 + d];
    *(bf16x8*)&dst[(size_t)d * LS_ + s0 + s8] = *(bf16x8*)tmp;
  }
}

// ---------------- causal flash attention: swapped-QK^T, in-register softmax ----------------
// wave owns 32 q rows (two 16-col fragments); lane carries 2 q-row softmax chains.
// head = bid & 255 -> all 4 blocks of a head share an XCD (K/V L2-resident).
__global__ __launch_bounds__(256) void k_attn(const u16* __restrict__ qh, const u16* __restrict__ kh,
                                              const u16* __restrict__ vt, u16* __restrict__ ytok){
  int bid = blockIdx.x;                 // 1024 blocks
  int head = bid & 255, pb = bid >> 8;  // pb 0..3; same-head blocks -> same wgid%8 -> same XCD
  int tid = threadIdx.x;
  int w = tid >> 6, l = tid & 63;
  int lr = l & 15, lg = l >> 4;
  // wave-job j in 0..15: {pb, 15-pb, pb+4, 11-pb} -> exactly 18 KV-tiles per block
  int j = (w == 0) ? pb : (w == 1) ? (15 - pb) : (w == 2) ? (pb + 4) : (11 - pb);
  int q0 = j * 32;
  int ntw = (j >> 1) + 1;               // exact KV-tile count

  const u16* Qp = qh + (size_t)head * LS_ * HD_;
  const u16* Kp = kh + (size_t)head * LS_ * HD_;
  const u16* Vp = vt + (size_t)head * HD_ * LS_;   // [d][s]
  int bg = head >> 4, h = head & 15;
  u16* Yb = ytok + (size_t)bg * LS_ * E_ + h * HD_;

  // Q fragments (B-operand): cols q0+mi*16+lr, k-halves kk
  bf16x8 aq[2][2];
  #pragma unroll
  for (int mi = 0; mi < 2; mi++)
    #pragma unroll
    for (int kk = 0; kk < 2; kk++)
      aq[mi][kk] = *(const bf16x8*)&Qp[(q0 + mi*16 + lr) * 64 + kk * 32 + lg * 8];

  __shared__ u16 Pl[4][32 * 72];        // per-wave P relayout buffer (no barriers)
  u16* Pw = Pl[w];

  f32x4 o[2][4] = {};                   // O[q=mi*16+lg*4+r][d=nd*16+lr]
  float mrun[2] = {-1e30f, -1e30f}, lrun[2] = {0.f, 0.f};

  for (int tkv = 0; tkv < ntw; tkv++){
    int kv0 = tkv * 64;
    // S^T = K Q^T : lane gets q=q0+mi*16+lr, kv=kv0+nk*16+lg*4+r
    f32x4 sa[2][4] = {};
    __builtin_amdgcn_s_setprio(1);
    #pragma unroll
    for (int nk = 0; nk < 4; nk++){
      bf16x8 k0 = *(const bf16x8*)&Kp[(kv0 + nk*16 + lr) * 64 + lg * 8];
      bf16x8 k1 = *(const bf16x8*)&Kp[(kv0 + nk*16 + lr) * 64 + 32 + lg * 8];
      #pragma unroll
      for (int mi = 0; mi < 2; mi++){
        sa[mi][nk] = MFMA16(k0, aq[mi][0], sa[mi][nk]);
        sa[mi][nk] = MFMA16(k1, aq[mi][1], sa[mi][nk]);
      }
    }
    __builtin_amdgcn_s_setprio(0);
    // causal mask (last tile only)
    if (kv0 + 63 > q0){
      #pragma unroll
      for (int mi = 0; mi < 2; mi++){
        int qg = q0 + mi*16 + lr;
        #pragma unroll
        for (int nk = 0; nk < 4; nk++)
          #pragma unroll
          for (int r = 0; r < 4; r++){
            int kg = kv0 + nk*16 + lg*4 + r;
            if (kg > qg) sa[mi][nk][r] = -1e30f;
          }
      }
    }
    float alpha[2];
    #pragma unroll
    for (int mi = 0; mi < 2; mi++){
      // in-register row max (16 values) + 2-step cross-lg reduce
      float pmax = sa[mi][0][0];
      #pragma unroll
      for (int nk = 0; nk < 4; nk++)
        #pragma unroll
        for (int r = 0; r < 4; r++) pmax = fmaxf(pmax, sa[mi][nk][r]);
      pmax = fmaxf(pmax, __shfl_xor(pmax, 16));
      pmax = fmaxf(pmax, __shfl_xor(pmax, 32));

      float mnew = fmaxf(mrun[mi], pmax);
      alpha[mi] = __expf(mrun[mi] - mnew);
      mrun[mi] = mnew;

      float psum = 0.f;
      #pragma unroll
      for (int nk = 0; nk < 4; nk++)
        #pragma unroll
        for (int r = 0; r < 4; r++){
          float pv = __expf(sa[mi][nk][r] - mnew);
          sa[mi][nk][r] = pv;
          psum += pv;
        }
      psum += __shfl_xor(psum, 16);
      psum += __shfl_xor(psum, 32);
      lrun[mi] = lrun[mi] * alpha[mi] + psum;
    }
    // rescale O: O's q index is mi*16 + lg*4+r -> alpha from lane (lg*4+r)
    #pragma unroll
    for (int r = 0; r < 4; r++){
      float a0 = __shfl(alpha[0], lg * 4 + r);
      float a1 = __shfl(alpha[1], lg * 4 + r);
      #pragma unroll
      for (int nd = 0; nd < 4; nd++){ o[0][nd][r] *= a0; o[1][nd][r] *= a1; }
    }
    // P (lane-local, kv-strided) -> per-wave LDS [q][kv] for A-fragment reads
    #pragma unroll
    for (int mi = 0; mi < 2; mi++)
      #pragma unroll
      for (int nk = 0; nk < 4; nk++){
        u32 d0 = (u32)f2bu(sa[mi][nk][0]) | ((u32)f2bu(sa[mi][nk][1]) << 16);
        u32 d1 = (u32)f2bu(sa[mi][nk][2]) | ((u32)f2bu(sa[mi][nk][3]) << 16);
        *(u32*)&Pw[(mi*16 + lr) * 72 + nk * 16 + lg * 4]     = d0;
        *(u32*)&Pw[(mi*16 + lr) * 72 + nk * 16 + lg * 4 + 2] = d1;
      }
    // O += P @ V : A=P rows(q), B=V^T cols(d)
    bf16x8 pa[2][2];
    #pragma unroll
    for (int mi = 0; mi < 2; mi++){
      pa[mi][0] = *(const bf16x8*)&Pw[(mi*16 + lr) * 72 + lg * 8];
      pa[mi][1] = *(const bf16x8*)&Pw[(mi*16 + lr) * 72 + 32 + lg * 8];
    }
    __builtin_amdgcn_s_setprio(1);
    #pragma unroll
    for (int nd = 0; nd < 4; nd++){
      bf16x8 bv0 = *(const bf16x8*)&Vp[(nd*16 + lr) * 512 + kv0 + lg * 8];
      bf16x8 bv1 = *(const bf16x8*)&Vp[(nd*16 + lr) * 512 + kv0 + 32 + lg * 8];
      #pragma unroll
      for (int mi = 0; mi < 2; mi++){
        o[mi][nd] = MFMA16(pa[mi][0], bv0, o[mi][nd]);
        o[mi][nd] = MFMA16(pa[mi][1], bv1, o[mi][nd]);
      }
    }
    __builtin_amdgcn_s_setprio(0);
  }

  // finalize: divide by l (redistribute like alpha), store token layout
  #pragma unroll
  for (int mi = 0; mi < 2; mi++){
    float linv = 1.f / lrun[mi];
    #pragma unroll
    for (int r = 0; r < 4; r++){
      float ir = __shfl(linv, lg * 4 + r);
      int qg = q0 + mi*16 + lg * 4 + r;
      #pragma unroll
      for (int nd = 0; nd < 4; nd++)
        Yb[(size_t)qg * E_ + nd * 16 + lr] = f2bu(o[mi][nd][r] * ir);
    }
  }
}

extern "C" void kernel_launch(void* const* d_in, const int* in_sizes, int n_in,
                              void* d_out, int out_size, void* d_ws, size_t ws_size,
                              hipStream_t stream){
  const float* x     = (const float*)d_in[0];
  const float* Wqkv  = (const float*)d_in[1];
  const float* lnw   = (const float*)d_in[2];
  const float* Wproj = (const float*)d_in[3];
  float* out = (float*)d_out;   // reference output dtype is float32

  u16* p = (u16*)d_ws;
  u16* xb     = p; p += (size_t)NTOK * E_;        // reused as ytok after GEMM1
  u16* wqkvT  = p; p += (size_t)3 * E_ * E_;
  u16* wprojT = p; p += (size_t)E_ * E_;
  u16* qkv    = p; p += (size_t)NTOK * 3 * E_;    // dead after norm_rope -> reused for vT
  u16* qhp    = p; p += (size_t)NTOK * E_;
  u16* khp    = p; p += (size_t)NTOK * E_;
  u16* vhp    = p; p += (size_t)NTOK * E_;
  float* ct = (float*)p;
  float* st = ct + LS_ * HD_;
  u16* vtp = qkv;   // [head][d][s], aliases dead qkv buffer

  k_conv_x<<<8192, 256, 0, stream>>>(x, xb);
  k_transpose<<<dim3(96, 32), 256, 0, stream>>>(Wqkv, wqkvT, 1024, 3072);
  k_transpose<<<dim3(32, 32), 256, 0, stream>>>(Wproj, wprojT, 1024, 1024);
  k_rope_table<<<128, 256, 0, stream>>>(ct, st);
  k_gemm_bt<u16><<<64 * 24, 256, 0, stream>>>(xb, wqkvT, qkv, NTOK, 3 * E_, E_);
  k_norm_rope<<<NTOK, 256, 0, stream>>>(qkv, lnw, ct, st, qhp, khp, vhp);
  k_vt<<<2048, 256, 0, stream>>>(vhp, vtp);
  k_attn<<<1024, 256, 0, stream>>>(qhp, khp, vtp, xb);           // xb now = y_tok
  k_gemm_bt<float><<<64 * 8, 256, 0, stream>>>(xb, wprojT, out, NTOK, E_, E_);
}

// Round 6
// 182.394 us; speedup vs baseline: 1.2754x; 1.1201x over previous
//
#include <hip/hip_runtime.h>

typedef unsigned short u16;
typedef unsigned int   u32;
typedef __attribute__((ext_vector_type(8))) short bf16x8;
typedef __attribute__((ext_vector_type(4))) float f32x4;

#define MFMA16(a,b,c) __builtin_amdgcn_mfma_f32_16x16x32_bf16((a),(b),(c),0,0,0)
#define GLD16(gp, lp) __builtin_amdgcn_global_load_lds((const __attribute__((address_space(1))) u32*)(gp), (__attribute__((address_space(3))) u32*)(lp), 16, 0, 0)

#define B_   2
#define NG_  8
#define LS_  512
#define E_   1024
#define NH_  16
#define HD_  64
#define NTOK 8192   // B_*NG_*LS_

__device__ __forceinline__ u16 f2bu(float f){
  u32 u = __builtin_bit_cast(u32, f);
  u32 r = u + 0x7FFFu + ((u >> 16) & 1u);   // RN-even
  return (u16)(r >> 16);
}
__device__ __forceinline__ float b2f(u16 h){
  u32 u = ((u32)h) << 16;
  return __builtin_bit_cast(float, u);
}

// ---------------- fp32 -> bf16 convert (x) ----------------
__global__ __launch_bounds__(256) void k_conv_x(const float* __restrict__ x, u16* __restrict__ xb){
  int i = blockIdx.x * 256 + threadIdx.x;
  float4 v = ((const float4*)x)[i];
  ((ushort4*)xb)[i] = make_ushort4(f2bu(v.x), f2bu(v.y), f2bu(v.z), f2bu(v.w));
}

// ---------------- weight transpose fp32[K][N] -> bf16[N][K] ----------------
__global__ __launch_bounds__(256) void k_transpose(const float* __restrict__ W, u16* __restrict__ WT,
                                                   int Kd, int Nd){
  __shared__ float tile[32][33];
  int tx = threadIdx.x & 31, ty = threadIdx.x >> 5;
  int c0 = blockIdx.x * 32, r0 = blockIdx.y * 32;
  #pragma unroll
  for (int i = 0; i < 4; i++)
    tile[ty + i*8][tx] = W[(size_t)(r0 + ty + i*8) * Nd + c0 + tx];
  __syncthreads();
  #pragma unroll
  for (int i = 0; i < 4; i++)
    WT[(size_t)(c0 + ty + i*8) * Kd + r0 + tx] = f2bu(tile[tx][ty + i*8]);
}

// ---------------- RoPE cos/sin table [LS][HD] ----------------
__global__ __launch_bounds__(256) void k_rope_table(float* __restrict__ ct, float* __restrict__ st){
  int i = blockIdx.x * 256 + threadIdx.x;   // 32768
  int s = i >> 6, d = i & 63, j = d & 31;
  float freq = powf(10000.f, -(4.f * (float)j + 1.f) / 64.f);
  float th = (float)s * freq;
  ct[i] = cosf(th);
  st[i] = sinf(th);
}

// ---------------- T2+T3+T4+T5 bf16 GEMM: C[M,N] = A[M,K] * Bt[N,K]^T ----------------
// 128x128 tile, BK=64, LDS double-buffer (64 KiB), counted vmcnt(8), raw s_barrier,
// XOR-swizzled LDS (linear gload_lds dest + inverse-swizzled global source).
// LDS layout: element (row, c[u16]) lives at u16 index row*64 + (c ^ ((row&7)<<3)).
template <typename OutT>
__global__ __launch_bounds__(256, 2) void k_gemm_bt(const u16* __restrict__ A, const u16* __restrict__ Bt,
                                                    OutT* __restrict__ C, int M, int N, int K){
  int nbn = N >> 7;
  int cpx = gridDim.x >> 3;
  int bid = (blockIdx.x & 7) * cpx + (blockIdx.x >> 3);   // bijective XCD swizzle (grid%8==0)
  int tm = bid / nbn, tn = bid % nbn;
  int tid = threadIdx.x;
  int w = tid >> 6, l = tid & 63;
  int lr = l & 15, lg = l >> 4;
  int wm = (w >> 1) * 64, wn = (w & 1) * 64;

  __shared__ u16 smem[2][2][128 * 64];   // [buf][A/B] = 64 KiB total

  const u16* Ab = A  + (size_t)(tm * 128) * K;
  const u16* Bb = Bt + (size_t)(tn * 128) * K;
  int NT = K >> 6;                        // 16 for K=1024

  int srow0 = tid >> 3, ssl = tid & 7;
  // stage K-tile t into buf s: 8x GLD16; source col pre-swizzled so linear LDS
  // write + swizzled read form the same involution (rule #21).
  auto stage = [&](int t, int s){
    int k0 = t << 6;
    #pragma unroll
    for (int q = 0; q < 4; q++){
      int row = q * 32 + srow0;
      int sc  = (ssl ^ (row & 7)) << 3;
      GLD16(Ab + (size_t)row * K + k0 + sc, &smem[s][0][q * 2048 + tid * 8]);
    }
    #pragma unroll
    for (int q = 0; q < 4; q++){
      int row = q * 32 + srow0;
      int sc  = (ssl ^ (row & 7)) << 3;
      GLD16(Bb + (size_t)row * K + k0 + sc, &smem[s][1][q * 2048 + tid * 8]);
    }
  };

  f32x4 acc[4][4] = {};

  stage(0, 0);
  stage(1, 1);
  asm volatile("s_waitcnt vmcnt(8)" ::: "memory");   // tile 0 landed, tile 1 in flight
  asm volatile("s_barrier" ::: "memory");

  for (int t = 0; t < NT; t++){
    int s = t & 1;
    const u16* As = smem[s][0];
    const u16* Bs = smem[s][1];
    bf16x8 bfr[4][2], afr[2][2];
    // phase A: read all B-frags + A m-half0, 16 MFMA
    #pragma unroll
    for (int j = 0; j < 4; j++){
      int rb = wn + j * 16 + lr;
      #pragma unroll
      for (int kk = 0; kk < 2; kk++)
        bfr[j][kk] = *(const bf16x8*)&Bs[rb * 64 + ((kk * 32 + lg * 8) ^ ((rb & 7) << 3))];
    }
    #pragma unroll
    for (int i = 0; i < 2; i++){
      int ra = wm + i * 16 + lr;
      #pragma unroll
      for (int kk = 0; kk < 2; kk++)
        afr[i][kk] = *(const bf16x8*)&As[ra * 64 + ((kk * 32 + lg * 8) ^ ((ra & 7) << 3))];
    }
    __builtin_amdgcn_s_setprio(1);
    #pragma unroll
    for (int i = 0; i < 2; i++)
      #pragma unroll
      for (int j = 0; j < 4; j++){
        acc[i][j] = MFMA16(afr[i][0], bfr[j][0], acc[i][j]);
        acc[i][j] = MFMA16(afr[i][1], bfr[j][1], acc[i][j]);
      }
    __builtin_amdgcn_s_setprio(0);
    asm volatile("s_barrier" ::: "memory");
    // phase B: read A m-half1, 16 MFMA
    #pragma unroll
    for (int i = 0; i < 2; i++){
      int ra = wm + (i + 2) * 16 + lr;
      #pragma unroll
      for (int kk = 0; kk < 2; kk++)
        afr[i][kk] = *(const bf16x8*)&As[ra * 64 + ((kk * 32 + lg * 8) ^ ((ra & 7) << 3))];
    }
    __builtin_amdgcn_s_setprio(1);
    #pragma unroll
    for (int i = 0; i < 2; i++)
      #pragma unroll
      for (int j = 0; j < 4; j++){
        acc[i + 2][j] = MFMA16(afr[i][0], bfr[j][0], acc[i + 2][j]);
        acc[i + 2][j] = MFMA16(afr[i][1], bfr[j][1], acc[i + 2][j]);
      }
    __builtin_amdgcn_s_setprio(0);
    asm volatile("s_barrier" ::: "memory");   // all waves done reading buf s
    if (t + 2 < NT){
      stage(t + 2, s);                         // overwrite retired buf
      asm volatile("s_waitcnt vmcnt(8)" ::: "memory");  // tile t+1 landed; t+2 stays in flight
      asm volatile("s_barrier" ::: "memory");
    } else if (t + 2 == NT){
      asm volatile("s_waitcnt vmcnt(0)" ::: "memory");  // final tile's loads (issued long ago)
      asm volatile("s_barrier" ::: "memory");
    }
  }

  #pragma unroll
  for (int i = 0; i < 4; i++)
    #pragma unroll
    for (int j = 0; j < 4; j++)
      #pragma unroll
      for (int r = 0; r < 4; r++){
        int row = tm * 128 + wm + i * 16 + lg * 4 + r;
        int col = tn * 128 + wn + j * 16 + lr;
        float v = acc[i][j][r];
        if constexpr (sizeof(OutT) == 2) C[(size_t)row * N + col] = f2bu(v);
        else                             C[(size_t)row * N + col] = v;
      }
}

// ---------------- RMSNorm + ln_w + RoPE + head split (q scaled by 1/8) ----------------
__global__ __launch_bounds__(256) void k_norm_rope(const u16* __restrict__ qkv, const float* __restrict__ lnw,
                                                   const float* __restrict__ ct, const float* __restrict__ st,
                                                   u16* __restrict__ qh, u16* __restrict__ kh, u16* __restrict__ vh){
  int tok = blockIdx.x;
  int t = threadIdx.x;
  int s = tok & (LS_ - 1);
  int bg = tok >> 9;
  const u16* row = qkv + (size_t)tok * 3072;
  int e0 = t * 4;

  ushort4 q4 = *(const ushort4*)&row[e0];
  ushort4 k4 = *(const ushort4*)&row[1024 + e0];
  ushort4 v4 = *(const ushort4*)&row[2048 + e0];
  float qf[4] = {b2f(q4.x), b2f(q4.y), b2f(q4.z), b2f(q4.w)};
  float kf[4] = {b2f(k4.x), b2f(k4.y), b2f(k4.z), b2f(k4.w)};

  float qss = 0.f, kss = 0.f;
  #pragma unroll
  for (int j = 0; j < 4; j++){ qss += qf[j]*qf[j]; kss += kf[j]*kf[j]; }
  #pragma unroll
  for (int o = 32; o; o >>= 1){ qss += __shfl_down(qss, o); kss += __shfl_down(kss, o); }
  __shared__ float redq[4], redk[4];
  if ((t & 63) == 0){ redq[t >> 6] = qss; redk[t >> 6] = kss; }
  __syncthreads();
  float qsum = redq[0] + redq[1] + redq[2] + redq[3];
  float ksum = redk[0] + redk[1] + redk[2] + redk[3];
  float qr = rsqrtf(qsum * (1.f / 1024.f) + 1e-6f);
  float kr = rsqrtf(ksum * (1.f / 1024.f) + 1e-6f);

  float qn[4], kn[4];
  #pragma unroll
  for (int j = 0; j < 4; j++){
    float wv = lnw[e0 + j];
    qn[j] = qf[j] * qr * wv;
    kn[j] = kf[j] * kr * wv;
  }
  int d0 = e0 & 63, h = e0 >> 6;
  const float* cr = ct + s * 64 + d0;
  const float* sr = st + s * 64 + d0;
  float qo[4], ko[4];
  #pragma unroll
  for (int p = 0; p < 4; p += 2){
    float c0 = cr[p], s0 = sr[p], c1 = cr[p+1], s1 = sr[p+1];
    qo[p]   = qn[p]   * c0 - qn[p+1] * s0;
    qo[p+1] = qn[p+1] * c1 + qn[p]   * s1;
    ko[p]   = kn[p]   * c0 - kn[p+1] * s0;
    ko[p+1] = kn[p+1] * c1 + kn[p]   * s1;
  }
  size_t oidx = (((size_t)bg * NH_ + h) * LS_ + s) * HD_ + d0;
  *(ushort4*)&qh[oidx] = make_ushort4(f2bu(qo[0]*0.125f), f2bu(qo[1]*0.125f), f2bu(qo[2]*0.125f), f2bu(qo[3]*0.125f));
  *(ushort4*)&kh[oidx] = make_ushort4(f2bu(ko[0]), f2bu(ko[1]), f2bu(ko[2]), f2bu(ko[3]));
  *(ushort4*)&vh[oidx] = v4;
}

// ---------------- V transpose: vh [head][s][d] -> vt [head][d][s] ----------------
__global__ __launch_bounds__(256) void k_vt(const u16* __restrict__ vh, u16* __restrict__ vt){
  int head = blockIdx.x >> 3, sb = blockIdx.x & 7;
  int s0 = sb * 64;
  __shared__ u16 t[64 * 72];
  const u16* src = vh + (size_t)head * LS_ * HD_ + (size_t)s0 * HD_;
  u16* dst = vt + (size_t)head * HD_ * LS_;
  #pragma unroll
  for (int p = 0; p < 2; p++){
    int idx = p * 256 + threadIdx.x;
    int r = idx >> 3, c8 = (idx & 7) * 8;
    *(bf16x8*)&t[r * 72 + c8] = *(const bf16x8*)&src[r * HD_ + c8];
  }
  __syncthreads();
  #pragma unroll
  for (int p = 0; p < 2; p++){
    int idx = p * 256 + threadIdx.x;
    int d = idx >> 3, s8 = (idx & 7) * 8;
    u16 tmp[8];
    #pragma unroll
    for (int j = 0; j < 8; j++) tmp[j] = t[(s8 + j) * 72 + d];
    *(bf16x8*)&dst[(size_t)d * LS_ + s0 + s8] = *(bf16x8*)tmp;
  }
}

// ---------------- causal flash attention: swapped-QK^T, in-register softmax ----------------
__global__ __launch_bounds__(256) void k_attn(const u16* __restrict__ qh, const u16* __restrict__ kh,
                                              const u16* __restrict__ vt, u16* __restrict__ ytok){
  int bid = blockIdx.x;                 // 1024 blocks
  int head = bid & 255, pb = bid >> 8;  // same-head blocks -> same XCD (K/V L2-resident)
  int tid = threadIdx.x;
  int w = tid >> 6, l = tid & 63;
  int lr = l & 15, lg = l >> 4;
  int j = (w == 0) ? pb : (w == 1) ? (15 - pb) : (w == 2) ? (pb + 4) : (11 - pb);
  int q0 = j * 32;
  int ntw = (j >> 1) + 1;               // exact KV-tile count

  const u16* Qp = qh + (size_t)head * LS_ * HD_;
  const u16* Kp = kh + (size_t)head * LS_ * HD_;
  const u16* Vp = vt + (size_t)head * HD_ * LS_;   // [d][s]
  int bg = head >> 4, h = head & 15;
  u16* Yb = ytok + (size_t)bg * LS_ * E_ + h * HD_;

  bf16x8 aq[2][2];
  #pragma unroll
  for (int mi = 0; mi < 2; mi++)
    #pragma unroll
    for (int kk = 0; kk < 2; kk++)
      aq[mi][kk] = *(const bf16x8*)&Qp[(q0 + mi*16 + lr) * 64 + kk * 32 + lg * 8];

  __shared__ u16 Pl[4][32 * 72];
  u16* Pw = Pl[w];

  f32x4 o[2][4] = {};
  float mrun[2] = {-1e30f, -1e30f}, lrun[2] = {0.f, 0.f};

  for (int tkv = 0; tkv < ntw; tkv++){
    int kv0 = tkv * 64;
    f32x4 sa[2][4] = {};
    __builtin_amdgcn_s_setprio(1);
    #pragma unroll
    for (int nk = 0; nk < 4; nk++){
      bf16x8 k0 = *(const bf16x8*)&Kp[(kv0 + nk*16 + lr) * 64 + lg * 8];
      bf16x8 k1 = *(const bf16x8*)&Kp[(kv0 + nk*16 + lr) * 64 + 32 + lg * 8];
      #pragma unroll
      for (int mi = 0; mi < 2; mi++){
        sa[mi][nk] = MFMA16(k0, aq[mi][0], sa[mi][nk]);
        sa[mi][nk] = MFMA16(k1, aq[mi][1], sa[mi][nk]);
      }
    }
    __builtin_amdgcn_s_setprio(0);
    if (kv0 + 63 > q0){
      #pragma unroll
      for (int mi = 0; mi < 2; mi++){
        int qg = q0 + mi*16 + lr;
        #pragma unroll
        for (int nk = 0; nk < 4; nk++)
          #pragma unroll
          for (int r = 0; r < 4; r++){
            int kg = kv0 + nk*16 + lg*4 + r;
            if (kg > qg) sa[mi][nk][r] = -1e30f;
          }
      }
    }
    float alpha[2];
    #pragma unroll
    for (int mi = 0; mi < 2; mi++){
      float pmax = sa[mi][0][0];
      #pragma unroll
      for (int nk = 0; nk < 4; nk++)
        #pragma unroll
        for (int r = 0; r < 4; r++) pmax = fmaxf(pmax, sa[mi][nk][r]);
      pmax = fmaxf(pmax, __shfl_xor(pmax, 16));
      pmax = fmaxf(pmax, __shfl_xor(pmax, 32));

      float mnew = fmaxf(mrun[mi], pmax);
      alpha[mi] = __expf(mrun[mi] - mnew);
      mrun[mi] = mnew;

      float psum = 0.f;
      #pragma unroll
      for (int nk = 0; nk < 4; nk++)
        #pragma unroll
        for (int r = 0; r < 4; r++){
          float pv = __expf(sa[mi][nk][r] - mnew);
          sa[mi][nk][r] = pv;
          psum += pv;
        }
      psum += __shfl_xor(psum, 16);
      psum += __shfl_xor(psum, 32);
      lrun[mi] = lrun[mi] * alpha[mi] + psum;
    }
    #pragma unroll
    for (int r = 0; r < 4; r++){
      float a0 = __shfl(alpha[0], lg * 4 + r);
      float a1 = __shfl(alpha[1], lg * 4 + r);
      #pragma unroll
      for (int nd = 0; nd < 4; nd++){ o[0][nd][r] *= a0; o[1][nd][r] *= a1; }
    }
    #pragma unroll
    for (int mi = 0; mi < 2; mi++)
      #pragma unroll
      for (int nk = 0; nk < 4; nk++){
        u32 d0 = (u32)f2bu(sa[mi][nk][0]) | ((u32)f2bu(sa[mi][nk][1]) << 16);
        u32 d1 = (u32)f2bu(sa[mi][nk][2]) | ((u32)f2bu(sa[mi][nk][3]) << 16);
        *(u32*)&Pw[(mi*16 + lr) * 72 + nk * 16 + lg * 4]     = d0;
        *(u32*)&Pw[(mi*16 + lr) * 72 + nk * 16 + lg * 4 + 2] = d1;
      }
    bf16x8 pa[2][2];
    #pragma unroll
    for (int mi = 0; mi < 2; mi++){
      pa[mi][0] = *(const bf16x8*)&Pw[(mi*16 + lr) * 72 + lg * 8];
      pa[mi][1] = *(const bf16x8*)&Pw[(mi*16 + lr) * 72 + 32 + lg * 8];
    }
    __builtin_amdgcn_s_setprio(1);
    #pragma unroll
    for (int nd = 0; nd < 4; nd++){
      bf16x8 bv0 = *(const bf16x8*)&Vp[(nd*16 + lr) * 512 + kv0 + lg * 8];
      bf16x8 bv1 = *(const bf16x8*)&Vp[(nd*16 + lr) * 512 + kv0 + 32 + lg * 8];
      #pragma unroll
      for (int mi = 0; mi < 2; mi++){
        o[mi][nd] = MFMA16(pa[mi][0], bv0, o[mi][nd]);
        o[mi][nd] = MFMA16(pa[mi][1], bv1, o[mi][nd]);
      }
    }
    __builtin_amdgcn_s_setprio(0);
  }

  #pragma unroll
  for (int mi = 0; mi < 2; mi++){
    float linv = 1.f / lrun[mi];
    #pragma unroll
    for (int r = 0; r < 4; r++){
      float ir = __shfl(linv, lg * 4 + r);
      int qg = q0 + mi*16 + lg * 4 + r;
      #pragma unroll
      for (int nd = 0; nd < 4; nd++)
        Yb[(size_t)qg * E_ + nd * 16 + lr] = f2bu(o[mi][nd][r] * ir);
    }
  }
}

extern "C" void kernel_launch(void* const* d_in, const int* in_sizes, int n_in,
                              void* d_out, int out_size, void* d_ws, size_t ws_size,
                              hipStream_t stream){
  const float* x     = (const float*)d_in[0];
  const float* Wqkv  = (const float*)d_in[1];
  const float* lnw   = (const float*)d_in[2];
  const float* Wproj = (const float*)d_in[3];
  float* out = (float*)d_out;   // reference output dtype is float32

  u16* p = (u16*)d_ws;
  u16* xb     = p; p += (size_t)NTOK * E_;        // reused as ytok after GEMM1
  u16* wqkvT  = p; p += (size_t)3 * E_ * E_;
  u16* wprojT = p; p += (size_t)E_ * E_;
  u16* qkv    = p; p += (size_t)NTOK * 3 * E_;    // dead after norm_rope -> reused for vT
  u16* qhp    = p; p += (size_t)NTOK * E_;
  u16* khp    = p; p += (size_t)NTOK * E_;
  u16* vhp    = p; p += (size_t)NTOK * E_;
  float* ct = (float*)p;
  float* st = ct + LS_ * HD_;
  u16* vtp = qkv;   // [head][d][s], aliases dead qkv buffer

  k_conv_x<<<8192, 256, 0, stream>>>(x, xb);
  k_transpose<<<dim3(96, 32), 256, 0, stream>>>(Wqkv, wqkvT, 1024, 3072);
  k_transpose<<<dim3(32, 32), 256, 0, stream>>>(Wproj, wprojT, 1024, 1024);
  k_rope_table<<<128, 256, 0, stream>>>(ct, st);
  k_gemm_bt<u16><<<64 * 24, 256, 0, stream>>>(xb, wqkvT, qkv, NTOK, 3 * E_, E_);
  k_norm_rope<<<NTOK, 256, 0, stream>>>(qkv, lnw, ct, st, qhp, khp, vhp);
  k_vt<<<2048, 256, 0, stream>>>(vhp, vtp);
  k_attn<<<1024, 256, 0, stream>>>(qhp, khp, vtp, xb);           // xb now = y_tok
  k_gemm_bt<float><<<64 * 8, 256, 0, stream>>>(xb, wprojT, out, NTOK, E_, E_);
}

// Round 7
// 166.554 us; speedup vs baseline: 1.3967x; 1.0951x over previous
//
#include <hip/hip_runtime.h>

typedef unsigned short u16;
typedef unsigned int   u32;
typedef __attribute__((ext_vector_type(8))) short bf16x8;
typedef __attribute__((ext_vector_type(4))) float f32x4;

#define MFMA16(a,b,c) __builtin_amdgcn_mfma_f32_16x16x32_bf16((a),(b),(c),0,0,0)
#define GLD16(gp, lp) __builtin_amdgcn_global_load_lds((const __attribute__((address_space(1))) u32*)(gp), (__attribute__((address_space(3))) u32*)(lp), 16, 0, 0)

#define B_   2
#define NG_  8
#define LS_  512
#define E_   1024
#define NH_  16
#define HD_  64
#define NTOK 8192   // B_*NG_*LS_

__device__ __forceinline__ u16 f2bu(float f){
  u32 u = __builtin_bit_cast(u32, f);
  u32 r = u + 0x7FFFu + ((u >> 16) & 1u);   // RN-even
  return (u16)(r >> 16);
}
__device__ __forceinline__ float b2f(u16 h){
  u32 u = ((u32)h) << 16;
  return __builtin_bit_cast(float, u);
}
__device__ __forceinline__ u32 pk2(float lo, float hi){   // 2x f32 -> packed bf16 (RNE)
  u32 r; asm("v_cvt_pk_bf16_f32 %0, %1, %2" : "=v"(r) : "v"(lo), "v"(hi)); return r;
}

// ---------------- fp32 -> bf16 convert (x) ----------------
__global__ __launch_bounds__(256) void k_conv_x(const float* __restrict__ x, u16* __restrict__ xb){
  int i = blockIdx.x * 256 + threadIdx.x;
  float4 v = ((const float4*)x)[i];
  ((ushort4*)xb)[i] = make_ushort4(f2bu(v.x), f2bu(v.y), f2bu(v.z), f2bu(v.w));
}

// ---------------- weight transpose fp32[K][N] -> bf16[N][K] ----------------
__global__ __launch_bounds__(256) void k_transpose(const float* __restrict__ W, u16* __restrict__ WT,
                                                   int Kd, int Nd){
  __shared__ float tile[32][33];
  int tx = threadIdx.x & 31, ty = threadIdx.x >> 5;
  int c0 = blockIdx.x * 32, r0 = blockIdx.y * 32;
  #pragma unroll
  for (int i = 0; i < 4; i++)
    tile[ty + i*8][tx] = W[(size_t)(r0 + ty + i*8) * Nd + c0 + tx];
  __syncthreads();
  #pragma unroll
  for (int i = 0; i < 4; i++)
    WT[(size_t)(c0 + ty + i*8) * Kd + r0 + tx] = f2bu(tile[tx][ty + i*8]);
}

// ---------------- RoPE cos/sin table [LS][HD] ----------------
__global__ __launch_bounds__(256) void k_rope_table(float* __restrict__ ct, float* __restrict__ st){
  int i = blockIdx.x * 256 + threadIdx.x;   // 32768
  int s = i >> 6, d = i & 63, j = d & 31;
  float freq = powf(10000.f, -(4.f * (float)j + 1.f) / 64.f);
  float th = (float)s * freq;
  ct[i] = cosf(th);
  st[i] = sinf(th);
}

// ---------------- T2+T3+T4+T5 bf16 GEMM: C[M,N] = A[M,K] * Bt[N,K]^T ----------------
// 128x128 tile, BK=64, LDS double-buffer (64 KiB), counted vmcnt(8), raw s_barrier,
// XOR-swizzled LDS (linear gload_lds dest + inverse-swizzled global source).
template <typename OutT>
__global__ __launch_bounds__(256, 2) void k_gemm_bt(const u16* __restrict__ A, const u16* __restrict__ Bt,
                                                    OutT* __restrict__ C, int M, int N, int K){
  int nbn = N >> 7;
  int cpx = gridDim.x >> 3;
  int bid = (blockIdx.x & 7) * cpx + (blockIdx.x >> 3);   // bijective XCD swizzle (grid%8==0)
  int tm = bid / nbn, tn = bid % nbn;
  int tid = threadIdx.x;
  int w = tid >> 6, l = tid & 63;
  int lr = l & 15, lg = l >> 4;
  int wm = (w >> 1) * 64, wn = (w & 1) * 64;

  __shared__ u16 smem[2][2][128 * 64];   // [buf][A/B] = 64 KiB total

  const u16* Ab = A  + (size_t)(tm * 128) * K;
  const u16* Bb = Bt + (size_t)(tn * 128) * K;
  int NT = K >> 6;                        // 16 for K=1024

  int srow0 = tid >> 3, ssl = tid & 7;
  auto stage = [&](int t, int s){
    int k0 = t << 6;
    #pragma unroll
    for (int q = 0; q < 4; q++){
      int row = q * 32 + srow0;
      int sc  = (ssl ^ (row & 7)) << 3;
      GLD16(Ab + (size_t)row * K + k0 + sc, &smem[s][0][q * 2048 + tid * 8]);
    }
    #pragma unroll
    for (int q = 0; q < 4; q++){
      int row = q * 32 + srow0;
      int sc  = (ssl ^ (row & 7)) << 3;
      GLD16(Bb + (size_t)row * K + k0 + sc, &smem[s][1][q * 2048 + tid * 8]);
    }
  };

  f32x4 acc[4][4] = {};

  stage(0, 0);
  stage(1, 1);
  asm volatile("s_waitcnt vmcnt(8)" ::: "memory");   // tile 0 landed, tile 1 in flight
  asm volatile("s_barrier" ::: "memory");

  for (int t = 0; t < NT; t++){
    int s = t & 1;
    const u16* As = smem[s][0];
    const u16* Bs = smem[s][1];
    bf16x8 bfr[4][2], afr[2][2];
    #pragma unroll
    for (int j = 0; j < 4; j++){
      int rb = wn + j * 16 + lr;
      #pragma unroll
      for (int kk = 0; kk < 2; kk++)
        bfr[j][kk] = *(const bf16x8*)&Bs[rb * 64 + ((kk * 32 + lg * 8) ^ ((rb & 7) << 3))];
    }
    #pragma unroll
    for (int i = 0; i < 2; i++){
      int ra = wm + i * 16 + lr;
      #pragma unroll
      for (int kk = 0; kk < 2; kk++)
        afr[i][kk] = *(const bf16x8*)&As[ra * 64 + ((kk * 32 + lg * 8) ^ ((ra & 7) << 3))];
    }
    __builtin_amdgcn_s_setprio(1);
    #pragma unroll
    for (int i = 0; i < 2; i++)
      #pragma unroll
      for (int j = 0; j < 4; j++){
        acc[i][j] = MFMA16(afr[i][0], bfr[j][0], acc[i][j]);
        acc[i][j] = MFMA16(afr[i][1], bfr[j][1], acc[i][j]);
      }
    __builtin_amdgcn_s_setprio(0);
    asm volatile("s_barrier" ::: "memory");
    #pragma unroll
    for (int i = 0; i < 2; i++){
      int ra = wm + (i + 2) * 16 + lr;
      #pragma unroll
      for (int kk = 0; kk < 2; kk++)
        afr[i][kk] = *(const bf16x8*)&As[ra * 64 + ((kk * 32 + lg * 8) ^ ((ra & 7) << 3))];
    }
    __builtin_amdgcn_s_setprio(1);
    #pragma unroll
    for (int i = 0; i < 2; i++)
      #pragma unroll
      for (int j = 0; j < 4; j++){
        acc[i + 2][j] = MFMA16(afr[i][0], bfr[j][0], acc[i + 2][j]);
        acc[i + 2][j] = MFMA16(afr[i][1], bfr[j][1], acc[i + 2][j]);
      }
    __builtin_amdgcn_s_setprio(0);
    asm volatile("s_barrier" ::: "memory");   // all waves done reading buf s
    if (t + 2 < NT){
      stage(t + 2, s);
      asm volatile("s_waitcnt vmcnt(8)" ::: "memory");
      asm volatile("s_barrier" ::: "memory");
    } else if (t + 2 == NT){
      asm volatile("s_waitcnt vmcnt(0)" ::: "memory");
      asm volatile("s_barrier" ::: "memory");
    }
  }

  #pragma unroll
  for (int i = 0; i < 4; i++)
    #pragma unroll
    for (int j = 0; j < 4; j++)
      #pragma unroll
      for (int r = 0; r < 4; r++){
        int row = tm * 128 + wm + i * 16 + lg * 4 + r;
        int col = tn * 128 + wn + j * 16 + lr;
        float v = acc[i][j][r];
        if constexpr (sizeof(OutT) == 2) C[(size_t)row * N + col] = f2bu(v);
        else                             C[(size_t)row * N + col] = v;
      }
}

// ---------------- RMSNorm + ln_w + RoPE + head split (q scaled by 1/8) ----------------
__global__ __launch_bounds__(256) void k_norm_rope(const u16* __restrict__ qkv, const float* __restrict__ lnw,
                                                   const float* __restrict__ ct, const float* __restrict__ st,
                                                   u16* __restrict__ qh, u16* __restrict__ kh, u16* __restrict__ vh){
  int tok = blockIdx.x;
  int t = threadIdx.x;
  int s = tok & (LS_ - 1);
  int bg = tok >> 9;
  const u16* row = qkv + (size_t)tok * 3072;
  int e0 = t * 4;

  ushort4 q4 = *(const ushort4*)&row[e0];
  ushort4 k4 = *(const ushort4*)&row[1024 + e0];
  ushort4 v4 = *(const ushort4*)&row[2048 + e0];
  float qf[4] = {b2f(q4.x), b2f(q4.y), b2f(q4.z), b2f(q4.w)};
  float kf[4] = {b2f(k4.x), b2f(k4.y), b2f(k4.z), b2f(k4.w)};

  float qss = 0.f, kss = 0.f;
  #pragma unroll
  for (int j = 0; j < 4; j++){ qss += qf[j]*qf[j]; kss += kf[j]*kf[j]; }
  #pragma unroll
  for (int o = 32; o; o >>= 1){ qss += __shfl_down(qss, o); kss += __shfl_down(kss, o); }
  __shared__ float redq[4], redk[4];
  if ((t & 63) == 0){ redq[t >> 6] = qss; redk[t >> 6] = kss; }
  __syncthreads();
  float qsum = redq[0] + redq[1] + redq[2] + redq[3];
  float ksum = redk[0] + redk[1] + redk[2] + redk[3];
  float qr = rsqrtf(qsum * (1.f / 1024.f) + 1e-6f);
  float kr = rsqrtf(ksum * (1.f / 1024.f) + 1e-6f);

  float qn[4], kn[4];
  #pragma unroll
  for (int j = 0; j < 4; j++){
    float wv = lnw[e0 + j];
    qn[j] = qf[j] * qr * wv;
    kn[j] = kf[j] * kr * wv;
  }
  int d0 = e0 & 63, h = e0 >> 6;
  const float* cr = ct + s * 64 + d0;
  const float* sr = st + s * 64 + d0;
  float qo[4], ko[4];
  #pragma unroll
  for (int p = 0; p < 4; p += 2){
    float c0 = cr[p], s0 = sr[p], c1 = cr[p+1], s1 = sr[p+1];
    qo[p]   = qn[p]   * c0 - qn[p+1] * s0;
    qo[p+1] = qn[p+1] * c1 + qn[p]   * s1;
    ko[p]   = kn[p]   * c0 - kn[p+1] * s0;
    ko[p+1] = kn[p+1] * c1 + kn[p]   * s1;
  }
  size_t oidx = (((size_t)bg * NH_ + h) * LS_ + s) * HD_ + d0;
  *(ushort4*)&qh[oidx] = make_ushort4(f2bu(qo[0]*0.125f), f2bu(qo[1]*0.125f), f2bu(qo[2]*0.125f), f2bu(qo[3]*0.125f));
  *(ushort4*)&kh[oidx] = make_ushort4(f2bu(ko[0]), f2bu(ko[1]), f2bu(ko[2]), f2bu(ko[3]));
  *(ushort4*)&vh[oidx] = v4;
}

// ---------------- V transpose: vh [head][s][d] -> vt [head][d][s] ----------------
__global__ __launch_bounds__(256) void k_vt(const u16* __restrict__ vh, u16* __restrict__ vt){
  int head = blockIdx.x >> 3, sb = blockIdx.x & 7;
  int s0 = sb * 64;
  __shared__ u16 t[64 * 72];
  const u16* src = vh + (size_t)head * LS_ * HD_ + (size_t)s0 * HD_;
  u16* dst = vt + (size_t)head * HD_ * LS_;
  #pragma unroll
  for (int p = 0; p < 2; p++){
    int idx = p * 256 + threadIdx.x;
    int r = idx >> 3, c8 = (idx & 7) * 8;
    *(bf16x8*)&t[r * 72 + c8] = *(const bf16x8*)&src[r * HD_ + c8];
  }
  __syncthreads();
  #pragma unroll
  for (int p = 0; p < 2; p++){
    int idx = p * 256 + threadIdx.x;
    int d = idx >> 3, s8 = (idx & 7) * 8;
    u16 tmp[8];
    #pragma unroll
    for (int j = 0; j < 8; j++) tmp[j] = t[(s8 + j) * 72 + d];
    *(bf16x8*)&dst[(size_t)d * LS_ + s0 + s8] = *(bf16x8*)tmp;
  }
}

// ---------------- causal flash attention: 1-wave blocks, swapped-QK^T, in-reg softmax ----------------
// grid 4096 x 64 threads. head = bid&255 (XCD-pinned K/V); j = 15-(bid>>8) heavy-first.
// Per wave: 32 q rows, K reg-reuse prefetch, early V loads, defer-max (THR=8).
__global__ __launch_bounds__(64) void k_attn(const u16* __restrict__ qh, const u16* __restrict__ kh,
                                             const u16* __restrict__ vt, u16* __restrict__ ytok){
  int bid = blockIdx.x;
  int head = bid & 255;
  int j = 15 - (bid >> 8);              // heavy jobs dispatched first
  int l = threadIdx.x & 63;
  int lr = l & 15, lg = l >> 4;
  int q0 = j * 32;
  int ntw = (j >> 1) + 1;               // exact KV-tile count

  const u16* Qp = qh + (size_t)head * LS_ * HD_;
  const u16* Kp = kh + (size_t)head * LS_ * HD_;
  const u16* Vp = vt + (size_t)head * HD_ * LS_;   // [d][s]
  int bg = head >> 4, h = head & 15;
  u16* Yb = ytok + (size_t)bg * LS_ * E_ + h * HD_;

  // Q fragments (B-operand): cols q0+mi*16+lr, k-halves kk
  bf16x8 aq[2][2];
  #pragma unroll
  for (int mi = 0; mi < 2; mi++)
    #pragma unroll
    for (int kk = 0; kk < 2; kk++)
      aq[mi][kk] = *(const bf16x8*)&Qp[(q0 + mi*16 + lr) * 64 + kk * 32 + lg * 8];

  __shared__ u16 Pw[32 * 72];           // per-wave P relayout buffer (1 wave/block)

  f32x4 o[2][4] = {};                   // O[q=mi*16+lg*4+r][d=nd*16+lr]
  float mrun[2] = {-1e30f, -1e30f}, lrun[2] = {0.f, 0.f};

  bf16x8 kr[4][2];                      // K tile registers (reused across tiles)
  auto loadK = [&](int kv0){
    #pragma unroll
    for (int nk = 0; nk < 4; nk++){
      kr[nk][0] = *(const bf16x8*)&Kp[(kv0 + nk*16 + lr) * 64 + lg * 8];
      kr[nk][1] = *(const bf16x8*)&Kp[(kv0 + nk*16 + lr) * 64 + 32 + lg * 8];
    }
  };
  loadK(0);

  for (int tkv = 0; tkv < ntw; tkv++){
    int kv0 = tkv * 64;
    // S^T = K Q^T : lane gets q=q0+mi*16+lr, kv=kv0+nk*16+lg*4+r
    f32x4 sa[2][4] = {};
    __builtin_amdgcn_s_setprio(1);
    #pragma unroll
    for (int nk = 0; nk < 4; nk++)
      #pragma unroll
      for (int mi = 0; mi < 2; mi++){
        sa[mi][nk] = MFMA16(kr[nk][0], aq[mi][0], sa[mi][nk]);
        sa[mi][nk] = MFMA16(kr[nk][1], aq[mi][1], sa[mi][nk]);
      }
    __builtin_amdgcn_s_setprio(0);
    // prefetch next K tile into the same regs (WAR after MFMA issue; hides K latency)
    if (tkv + 1 < ntw) loadK(kv0 + 64);
    // early V loads for THIS tile (arrive during softmax)
    bf16x8 vr[4][2];
    #pragma unroll
    for (int nd = 0; nd < 4; nd++){
      vr[nd][0] = *(const bf16x8*)&Vp[(nd*16 + lr) * 512 + kv0 + lg * 8];
      vr[nd][1] = *(const bf16x8*)&Vp[(nd*16 + lr) * 512 + kv0 + 32 + lg * 8];
    }
    // causal mask (last tile only)
    if (kv0 + 63 > q0){
      #pragma unroll
      for (int mi = 0; mi < 2; mi++){
        int qg = q0 + mi*16 + lr;
        #pragma unroll
        for (int nk = 0; nk < 4; nk++)
          #pragma unroll
          for (int r = 0; r < 4; r++){
            int kg = kv0 + nk*16 + lg*4 + r;
            if (kg > qg) sa[mi][nk][r] = -1e30f;
          }
      }
    }
    // row max (in-reg 16 + 2 cross-lane steps)
    float pmax[2];
    #pragma unroll
    for (int mi = 0; mi < 2; mi++){
      float pm = sa[mi][0][0];
      #pragma unroll
      for (int nk = 0; nk < 4; nk++)
        #pragma unroll
        for (int r = 0; r < 4; r++) pm = fmaxf(pm, sa[mi][nk][r]);
      pm = fmaxf(pm, __shfl_xor(pm, 16));
      pm = fmaxf(pm, __shfl_xor(pm, 32));
      pmax[mi] = pm;
    }
    // defer-max: only rescale when the running max grew by > 8
    float dm = fmaxf(pmax[0] - mrun[0], pmax[1] - mrun[1]);
    if (!__all(dm <= 8.f)){
      float alpha[2];
      #pragma unroll
      for (int mi = 0; mi < 2; mi++){
        float mnew = fmaxf(mrun[mi], pmax[mi]);
        alpha[mi] = __expf(mrun[mi] - mnew);
        mrun[mi] = mnew;
        lrun[mi] *= alpha[mi];
      }
      #pragma unroll
      for (int r = 0; r < 4; r++){
        float a0 = __shfl(alpha[0], lg * 4 + r);
        float a1 = __shfl(alpha[1], lg * 4 + r);
        #pragma unroll
        for (int nd = 0; nd < 4; nd++){ o[0][nd][r] *= a0; o[1][nd][r] *= a1; }
      }
    }
    // P = exp(S - m), row sums
    #pragma unroll
    for (int mi = 0; mi < 2; mi++){
      float psum = 0.f;
      #pragma unroll
      for (int nk = 0; nk < 4; nk++)
        #pragma unroll
        for (int r = 0; r < 4; r++){
          float pv = __expf(sa[mi][nk][r] - mrun[mi]);
          sa[mi][nk][r] = pv;
          psum += pv;
        }
      psum += __shfl_xor(psum, 16);
      psum += __shfl_xor(psum, 32);
      lrun[mi] += psum;
    }
    // P (lane-local, kv-strided) -> per-wave LDS [q][kv] for A-fragment reads
    #pragma unroll
    for (int mi = 0; mi < 2; mi++)
      #pragma unroll
      for (int nk = 0; nk < 4; nk++){
        *(u32*)&Pw[(mi*16 + lr) * 72 + nk * 16 + lg * 4]     = pk2(sa[mi][nk][0], sa[mi][nk][1]);
        *(u32*)&Pw[(mi*16 + lr) * 72 + nk * 16 + lg * 4 + 2] = pk2(sa[mi][nk][2], sa[mi][nk][3]);
      }
    bf16x8 pa[2][2];
    #pragma unroll
    for (int mi = 0; mi < 2; mi++){
      pa[mi][0] = *(const bf16x8*)&Pw[(mi*16 + lr) * 72 + lg * 8];
      pa[mi][1] = *(const bf16x8*)&Pw[(mi*16 + lr) * 72 + 32 + lg * 8];
    }
    // O += P @ V (V already in regs)
    __builtin_amdgcn_s_setprio(1);
    #pragma unroll
    for (int nd = 0; nd < 4; nd++)
      #pragma unroll
      for (int mi = 0; mi < 2; mi++){
        o[mi][nd] = MFMA16(pa[mi][0], vr[nd][0], o[mi][nd]);
        o[mi][nd] = MFMA16(pa[mi][1], vr[nd][1], o[mi][nd]);
      }
    __builtin_amdgcn_s_setprio(0);
  }

  // finalize: divide by l (redistribute like alpha), store token layout
  #pragma unroll
  for (int mi = 0; mi < 2; mi++){
    float linv = 1.f / lrun[mi];
    #pragma unroll
    for (int r = 0; r < 4; r++){
      float ir = __shfl(linv, lg * 4 + r);
      int qg = q0 + mi*16 + lg * 4 + r;
      #pragma unroll
      for (int nd = 0; nd < 4; nd++)
        Yb[(size_t)qg * E_ + nd * 16 + lr] = f2bu(o[mi][nd][r] * ir);
    }
  }
}

extern "C" void kernel_launch(void* const* d_in, const int* in_sizes, int n_in,
                              void* d_out, int out_size, void* d_ws, size_t ws_size,
                              hipStream_t stream){
  const float* x     = (const float*)d_in[0];
  const float* Wqkv  = (const float*)d_in[1];
  const float* lnw   = (const float*)d_in[2];
  const float* Wproj = (const float*)d_in[3];
  float* out = (float*)d_out;   // reference output dtype is float32

  u16* p = (u16*)d_ws;
  u16* xb     = p; p += (size_t)NTOK * E_;        // reused as ytok after GEMM1
  u16* wqkvT  = p; p += (size_t)3 * E_ * E_;
  u16* wprojT = p; p += (size_t)E_ * E_;
  u16* qkv    = p; p += (size_t)NTOK * 3 * E_;    // dead after norm_rope -> reused for vT
  u16* qhp    = p; p += (size_t)NTOK * E_;
  u16* khp    = p; p += (size_t)NTOK * E_;
  u16* vhp    = p; p += (size_t)NTOK * E_;
  float* ct = (float*)p;
  float* st = ct + LS_ * HD_;
  u16* vtp = qkv;   // [head][d][s], aliases dead qkv buffer

  k_conv_x<<<8192, 256, 0, stream>>>(x, xb);
  k_transpose<<<dim3(96, 32), 256, 0, stream>>>(Wqkv, wqkvT, 1024, 3072);
  k_transpose<<<dim3(32, 32), 256, 0, stream>>>(Wproj, wprojT, 1024, 1024);
  k_rope_table<<<128, 256, 0, stream>>>(ct, st);
  k_gemm_bt<u16><<<64 * 24, 256, 0, stream>>>(xb, wqkvT, qkv, NTOK, 3 * E_, E_);
  k_norm_rope<<<NTOK, 256, 0, stream>>>(qkv, lnw, ct, st, qhp, khp, vhp);
  k_vt<<<2048, 256, 0, stream>>>(vhp, vtp);
  k_attn<<<4096, 64, 0, stream>>>(qhp, khp, vtp, xb);            // xb now = y_tok
  k_gemm_bt<float><<<64 * 8, 256, 0, stream>>>(xb, wprojT, out, NTOK, E_, E_);
}